// Round 1
// baseline (1139.155 us; speedup 1.0000x reference)
//
#include <hip/hip_runtime.h>

#define B_    512
#define V_    50000
#define KT    200     // topics
#define HH    300     // embedding dim
#define HIDN  800     // hidden
#define KP    224     // padded topic dim (7*32)
#define HP    320     // padded embedding dim (10*32)

typedef __attribute__((ext_vector_type(4))) float  f32x4;
typedef __attribute__((ext_vector_type(8))) short  s8v;
typedef __attribute__((ext_vector_type(8))) __bf16 bf16x8;

static __device__ __forceinline__ f32x4 mfma16(s8v a, s8v b, f32x4 c){
  return __builtin_amdgcn_mfma_f32_16x16x32_bf16(
      __builtin_bit_cast(bf16x8, a), __builtin_bit_cast(bf16x8, b), c, 0, 0, 0);
}
static __device__ __forceinline__ short f2bf(float f){
  unsigned u = __float_as_uint(f);
  u = (u + 0x7fffu + ((u >> 16) & 1u)) >> 16;
  return (short)u;
}
static __device__ __forceinline__ float bf2f(short s){
  return __uint_as_float(((unsigned)(unsigned short)s) << 16);
}

// ---------------- zero init ----------------
__global__ void kzero(float* p, long n){
  long i = blockIdx.x * (long)blockDim.x + threadIdx.x;
  long st = (long)gridDim.x * blockDim.x;
  for(; i < n; i += st) p[i] = 0.f;
}

// ---------------- fp32 -> bf16 convert (n multiple of 4) ----------------
__global__ void kconv(const float* __restrict__ src, short* __restrict__ dst, long n4){
  long i = blockIdx.x * (long)blockDim.x + threadIdx.x;
  long st = (long)gridDim.x * blockDim.x;
  for(; i < n4; i += st){
    float4 v = ((const float4*)src)[i];
    short4 o;
    o.x = f2bf(v.x); o.y = f2bf(v.y); o.z = f2bf(v.z); o.w = f2bf(v.w);
    ((short4*)dst)[i] = o;
  }
}

// ---------------- fp32 -> bf16 with row padding (blockDim = kpad) ----------------
__global__ void kconvpad(const float* __restrict__ src, short* __restrict__ dst,
                         int kin, int kpad){
  int r = blockIdx.x, c = threadIdx.x;
  float v = (c < kin) ? src[(long)r * kin + c] : 0.f;
  dst[(long)r * kpad + c] = f2bf(v);
}

// ---------------- GEMM1: hid_acc += bows @ W1 (split-K, atomic) ----------------
// A = bows_b (512 x 50000 bf16), B = W1b (50000 x 800 bf16), C = hid_acc (512x800 f32)
__global__ __launch_bounds__(256) void k_gemm1(const short* __restrict__ Ab,
                                               const short* __restrict__ Bb,
                                               float* __restrict__ Cacc){
  const int N = HIDN; const long Kd = V_;
  __shared__ short As[128 * 40];
  __shared__ short Bs[128 * 40];
  int tid = threadIdx.x, w = tid >> 6, lane = tid & 63, lm = lane & 15, q = lane >> 4;
  int m0 = blockIdx.x * 128, n0 = blockIdx.y * 128;
  long kstart = (long)blockIdx.z * 1568;
  long kend = kstart + 1568; if(kend > Kd) kend = Kd;
  f32x4 acc[2][8];
  #pragma unroll
  for(int i = 0; i < 2; i++)
    #pragma unroll
    for(int j = 0; j < 8; j++) acc[i][j] = (f32x4){0.f,0.f,0.f,0.f};

  for(long kb = kstart; kb < kend; kb += 32){
    #pragma unroll
    for(int c0 = 0; c0 < 2; c0++){
      int c = tid + c0 * 256;
      int r = c >> 2, off = (c & 3) * 8;
      long kg = kb + off;
      s8v v = {0,0,0,0,0,0,0,0};
      if(kg < Kd) v = *(const s8v*)&Ab[(long)(m0 + r) * Kd + kg];
      *(s8v*)&As[r * 40 + off] = v;
    }
    #pragma unroll
    for(int c0 = 0; c0 < 2; c0++){
      int c = tid + c0 * 256;
      int kr = c >> 4, noff = (c & 15) * 8;
      long kg = kb + kr; int ng = n0 + noff;
      s8v v = {0,0,0,0,0,0,0,0};
      if(kg < Kd && ng < N) v = *(const s8v*)&Bb[kg * (long)N + ng];
      #pragma unroll
      for(int j = 0; j < 8; j++) Bs[(noff + j) * 40 + kr] = v[j];
    }
    __syncthreads();
    s8v af[2], bfr[8];
    #pragma unroll
    for(int i = 0; i < 2; i++) af[i]  = *(const s8v*)&As[(w * 32 + i * 16 + lm) * 40 + q * 8];
    #pragma unroll
    for(int j = 0; j < 8; j++) bfr[j] = *(const s8v*)&Bs[(j * 16 + lm) * 40 + q * 8];
    #pragma unroll
    for(int i = 0; i < 2; i++)
      #pragma unroll
      for(int j = 0; j < 8; j++)
        acc[i][j] = mfma16(af[i], bfr[j], acc[i][j]);
    __syncthreads();
  }
  #pragma unroll
  for(int i = 0; i < 2; i++)
    #pragma unroll
    for(int j = 0; j < 8; j++){
      int gm = m0 + w * 32 + i * 16 + q * 4;
      int gn = n0 + j * 16 + lm;
      if(gn < N){
        #pragma unroll
        for(int r = 0; r < 4; r++) atomicAdd(&Cacc[(long)(gm + r) * N + gn], acc[i][j][r]);
      }
    }
}

// ---------------- theta: relu(hid+b1) @ W2 + b2 -> softplus -> softmax ----------------
__global__ __launch_bounds__(256) void k_theta(const float* __restrict__ hid_acc,
                                               const float* __restrict__ b1,
                                               const float* __restrict__ W2,
                                               const float* __restrict__ b2,
                                               short* __restrict__ theta_b,
                                               short* __restrict__ thetan_b,
                                               float* __restrict__ thetan_f){
  __shared__ float hrow[HIDN];
  __shared__ float thl[256];
  __shared__ float redm[4], reds[4];
  int b = blockIdx.x, tid = threadIdx.x;
  for(int h = tid; h < HIDN; h += 256){
    float x = hid_acc[(long)b * HIDN + h] + b1[h];
    hrow[h] = x > 0.f ? x : 0.f;
  }
  __syncthreads();
  float th = 0.f;
  if(tid < KT){
    float z = b2[tid];
    #pragma unroll 4
    for(int h = 0; h < HIDN; h++) z += hrow[h] * W2[h * KT + tid];
    th = (z > 0.f ? z : 0.f) + log1pf(expf(-fabsf(z)));   // softplus
  }
  thl[tid] = (tid < KT) ? th : -1e30f;
  __syncthreads();
  float m = thl[tid];
  #pragma unroll
  for(int s = 32; s >= 1; s >>= 1) m = fmaxf(m, __shfl_xor(m, s, 64));
  if((tid & 63) == 0) redm[tid >> 6] = m;
  __syncthreads();
  float mx = fmaxf(fmaxf(redm[0], redm[1]), fmaxf(redm[2], redm[3]));
  float e = (tid < KT) ? expf(th - mx) : 0.f;
  float s_ = e;
  #pragma unroll
  for(int s = 32; s >= 1; s >>= 1) s_ += __shfl_xor(s_, s, 64);
  if((tid & 63) == 0) reds[tid >> 6] = s_;
  __syncthreads();
  float sum = reds[0] + reds[1] + reds[2] + reds[3];
  if(tid < KP){
    short tb  = (tid < KT) ? f2bf(th) : (short)0;
    short tnb = (tid < KT) ? f2bf(e / sum) : (short)0;
    theta_b [(long)b * KP + tid] = tb;
    thetan_b[(long)b * KP + tid] = tnb;
  }
  if(tid < KT) thetan_f[(long)b * KT + tid] = e / sum;
}

// ---------------- inner = rho @ alpha^T ; write dis_b, cd_b (bf16, V x KP), sumexp ----------------
__global__ __launch_bounds__(256) void k_inner(const short* __restrict__ rho_p,
                                               const short* __restrict__ alpha_p,
                                               short* __restrict__ dis_b,
                                               short* __restrict__ cd_b,
                                               float* __restrict__ sumexp){
  __shared__ short As[128 * 40];
  __shared__ short Bs[64 * 40];
  __shared__ short tDis[128 * 72];
  __shared__ short tCd [128 * 72];
  __shared__ float sume_l[64];
  int tid = threadIdx.x, w = tid >> 6, lane = tid & 63, lm = lane & 15, q = lane >> 4;
  int v0 = blockIdx.x * 128, t0 = blockIdx.y * 64;
  if(tid < 64) sume_l[tid] = 0.f;
  __syncthreads();
  f32x4 acc[2][4];
  #pragma unroll
  for(int i = 0; i < 2; i++)
    #pragma unroll
    for(int j = 0; j < 4; j++) acc[i][j] = (f32x4){0.f,0.f,0.f,0.f};

  for(int h0 = 0; h0 < HP; h0 += 32){
    #pragma unroll
    for(int c0 = 0; c0 < 2; c0++){
      int c = tid + c0 * 256;
      int r = c >> 2, off = (c & 3) * 8;
      int vg = v0 + r;
      s8v v = {0,0,0,0,0,0,0,0};
      if(vg < V_) v = *(const s8v*)&rho_p[(long)vg * HP + h0 + off];
      *(s8v*)&As[r * 40 + off] = v;
    }
    {
      int r = tid >> 2, off = (tid & 3) * 8;
      int tg = t0 + r;
      s8v v = {0,0,0,0,0,0,0,0};
      if(tg < KT) v = *(const s8v*)&alpha_p[(long)tg * HP + h0 + off];
      *(s8v*)&Bs[r * 40 + off] = v;
    }
    __syncthreads();
    s8v af[2], bfr[4];
    #pragma unroll
    for(int i = 0; i < 2; i++) af[i]  = *(const s8v*)&As[(w * 32 + i * 16 + lm) * 40 + q * 8];
    #pragma unroll
    for(int j = 0; j < 4; j++) bfr[j] = *(const s8v*)&Bs[(j * 16 + lm) * 40 + q * 8];
    #pragma unroll
    for(int i = 0; i < 2; i++)
      #pragma unroll
      for(int j = 0; j < 4; j++)
        acc[i][j] = mfma16(af[i], bfr[j], acc[i][j]);
    __syncthreads();
  }
  // epilogue: dis/cd into LDS tile + per-t exp sums
  #pragma unroll
  for(int i = 0; i < 2; i++)
    #pragma unroll
    for(int j = 0; j < 4; j++){
      int tg = t0 + j * 16 + lm;
      float s4 = 0.f;
      #pragma unroll
      for(int r = 0; r < 4; r++){
        int vloc = w * 32 + i * 16 + q * 4 + r;
        int vg = v0 + vloc;
        float x = acc[i][j][r];
        float e1 = __expf(x);  e1 = fminf(fmaxf(e1, 1e-30f), 1e10f);
        float e2 = __expf(-x); e2 = fminf(fmaxf(e2, 1e-30f), 1e10f);
        float cd = e1 * e2;
        bool valid = (vg < V_) && (tg < KT);
        float dv = valid ? e1 : 0.f;
        float cv = valid ? cd : 0.f;
        tDis[vloc * 72 + (j * 16 + lm)] = f2bf(dv);
        tCd [vloc * 72 + (j * 16 + lm)] = f2bf(cv);
        s4 += dv;
      }
      s4 += __shfl_xor(s4, 16, 64);
      s4 += __shfl_xor(s4, 32, 64);
      if(q == 0) atomicAdd(&sume_l[j * 16 + lm], s4);
    }
  __syncthreads();
  for(int c = tid; c < 1024; c += 256){
    int r = c >> 3, off8 = (c & 7) * 8;
    int vg = v0 + r, tg = t0 + off8;
    if(vg < V_ && tg < KP){
      *(s8v*)&dis_b[(long)vg * KP + tg] = *(const s8v*)&tDis[r * 72 + off8];
      *(s8v*)&cd_b [(long)vg * KP + tg] = *(const s8v*)&tCd [r * 72 + off8];
    }
  }
  if(tid < 64 && (t0 + tid) < KT) atomicAdd(&sumexp[t0 + tid], sume_l[tid]);
}

// ---------------- fused consumer: num/den/recon GEMMs + forward/ntok/tm reductions ----------------
__global__ __launch_bounds__(256) void k_consumer(const short* __restrict__ dis_b,
                                                  const short* __restrict__ cd_b,
                                                  const short* __restrict__ theta_b,
                                                  const short* __restrict__ thetan_b,
                                                  const float* __restrict__ sumexp,
                                                  const float* __restrict__ bows,
                                                  float* __restrict__ fwd_acc,
                                                  float* __restrict__ ntok_acc,
                                                  float* __restrict__ tm_acc){
  __shared__ float fwd_l[B_];
  __shared__ float ntok_l[B_];
  __shared__ float tm_l;
  int tid = threadIdx.x;
  for(int i = tid; i < B_; i += 256){ fwd_l[i] = 0.f; ntok_l[i] = 0.f; }
  if(tid == 0) tm_l = 0.f;
  __syncthreads();
  int w = tid >> 6, lane = tid & 63, lm = lane & 15, q = lane >> 4;
  int v0 = blockIdx.x * 64;
  int vb = v0 + w * 16;
  bool vvalid = vb < V_;   // V_ % 16 == 0 -> whole 16-row group valid or not

  s8v disf[7], cdf[7], phif[7];
  #pragma unroll
  for(int i = 0; i < 7; i++){
    int tc = i * 32 + q * 8;
    s8v d = {0,0,0,0,0,0,0,0}, c = {0,0,0,0,0,0,0,0};
    if(vvalid){
      d = *(const s8v*)&dis_b[(long)(vb + lm) * KP + tc];
      c = *(const s8v*)&cd_b [(long)(vb + lm) * KP + tc];
    }
    disf[i] = d; cdf[i] = c;
    s8v p;
    #pragma unroll
    for(int j = 0; j < 8; j++){
      int t = tc + j;
      float se = (t < KT) ? sumexp[t] : 1.f;
      p[j] = f2bf(bf2f(d[j]) / se);
    }
    phif[i] = p;
  }

  float tmreg = 0.f;
  for(int cb = 0; cb < 32; cb++){
    int b0 = cb * 16;
    f32x4 aN = {0.f,0.f,0.f,0.f}, aD = {0.f,0.f,0.f,0.f}, aR = {0.f,0.f,0.f,0.f};
    #pragma unroll
    for(int i = 0; i < 7; i++){
      long off = (long)(b0 + lm) * KP + i * 32 + q * 8;
      s8v tn = *(const s8v*)&thetan_b[off];
      s8v tt = *(const s8v*)&theta_b[off];
      aD = mfma16(disf[i], tn, aD);
      aN = mfma16(cdf[i],  tn, aN);
      aR = mfma16(phif[i], tt, aR);
    }
    int bg = b0 + lm;
    f32x4 bw = {0.f,0.f,0.f,0.f};
    if(vvalid) bw = *(const f32x4*)&bows[(long)bg * V_ + vb + q * 4];
    float fwd_p = 0.f, nt_p = 0.f;
    #pragma unroll
    for(int r = 0; r < 4; r++){
      float den = aD[r] + 1e-30f;
      float f = aN[r] / den;
      float rec = aR[r];
      float bv = bw[r];
      fwd_p += bv * f;
      nt_p  += bv;
      float lg = bv < 1.5f ? 0.f : (bv < 2.5f ? 0.69314718056f :
                 (bv < 3.5f ? 1.79175946923f : 3.17805383035f));
      tmreg += bv * __logf(rec + 1e-10f) - rec - lg;
    }
    fwd_p += __shfl_xor(fwd_p, 16, 64); fwd_p += __shfl_xor(fwd_p, 32, 64);
    nt_p  += __shfl_xor(nt_p, 16, 64);  nt_p  += __shfl_xor(nt_p, 32, 64);
    if(q == 0){
      atomicAdd(&fwd_l[bg], fwd_p);
      atomicAdd(&ntok_l[bg], nt_p);
    }
  }
  #pragma unroll
  for(int s = 32; s >= 1; s >>= 1) tmreg += __shfl_xor(tmreg, s, 64);
  if(lane == 0) atomicAdd(&tm_l, tmreg);
  __syncthreads();
  for(int i = tid; i < B_; i += 256){
    atomicAdd(&fwd_acc[i], fwd_l[i]);
    atomicAdd(&ntok_acc[i], ntok_l[i]);
  }
  if(tid == 0) atomicAdd(tm_acc, tm_l);
}

// ---------------- colsum = bows@dis, A = bows@cd (split-K, atomic) ----------------
__global__ __launch_bounds__(256) void k_colsum(const short* __restrict__ bows_b,
                                                const short* __restrict__ dis_b,
                                                const short* __restrict__ cd_b,
                                                float* __restrict__ colsum_acc,
                                                float* __restrict__ A_acc){
  __shared__ short As[128 * 40];
  __shared__ short BsD[64 * 40];
  __shared__ short BsC[64 * 40];
  int tid = threadIdx.x, w = tid >> 6, lane = tid & 63, lm = lane & 15, q = lane >> 4;
  int m0 = blockIdx.x * 128, t0 = blockIdx.y * 64;
  long kstart = (long)blockIdx.z * 1056;
  long kend = kstart + 1056; if(kend > V_) kend = V_;
  f32x4 accD[2][4], accC[2][4];
  #pragma unroll
  for(int i = 0; i < 2; i++)
    #pragma unroll
    for(int j = 0; j < 4; j++){ accD[i][j] = (f32x4){0.f,0.f,0.f,0.f}; accC[i][j] = (f32x4){0.f,0.f,0.f,0.f}; }

  for(long kb = kstart; kb < kend; kb += 32){
    #pragma unroll
    for(int c0 = 0; c0 < 2; c0++){
      int c = tid + c0 * 256;
      int r = c >> 2, off = (c & 3) * 8;
      long kg = kb + off;
      s8v v = {0,0,0,0,0,0,0,0};
      if(kg < V_) v = *(const s8v*)&bows_b[(long)(m0 + r) * V_ + kg];
      *(s8v*)&As[r * 40 + off] = v;
    }
    {
      int vr = tid >> 3, toff = (tid & 7) * 8;
      long vg = kb + vr; int tg = t0 + toff;
      s8v vd = {0,0,0,0,0,0,0,0}, vc = {0,0,0,0,0,0,0,0};
      if(vg < V_ && tg < KP){
        vd = *(const s8v*)&dis_b[vg * KP + tg];
        vc = *(const s8v*)&cd_b [vg * KP + tg];
      }
      #pragma unroll
      for(int j = 0; j < 8; j++){
        BsD[(toff + j) * 40 + vr] = vd[j];
        BsC[(toff + j) * 40 + vr] = vc[j];
      }
    }
    __syncthreads();
    s8v af[2], bd[4], bc[4];
    #pragma unroll
    for(int i = 0; i < 2; i++) af[i] = *(const s8v*)&As[(w * 32 + i * 16 + lm) * 40 + q * 8];
    #pragma unroll
    for(int j = 0; j < 4; j++){
      bd[j] = *(const s8v*)&BsD[(j * 16 + lm) * 40 + q * 8];
      bc[j] = *(const s8v*)&BsC[(j * 16 + lm) * 40 + q * 8];
    }
    #pragma unroll
    for(int i = 0; i < 2; i++)
      #pragma unroll
      for(int j = 0; j < 4; j++){
        accD[i][j] = mfma16(af[i], bd[j], accD[i][j]);
        accC[i][j] = mfma16(af[i], bc[j], accC[i][j]);
      }
    __syncthreads();
  }
  #pragma unroll
  for(int i = 0; i < 2; i++)
    #pragma unroll
    for(int j = 0; j < 4; j++){
      int doc = m0 + w * 32 + i * 16 + q * 4;
      int tg = t0 + j * 16 + lm;
      if(tg < KT){
        #pragma unroll
        for(int r = 0; r < 4; r++){
          atomicAdd(&colsum_acc[(long)(doc + r) * KT + tg], accD[i][j][r]);
          atomicAdd(&A_acc     [(long)(doc + r) * KT + tg], accC[i][j][r]);
        }
      }
    }
}

// ---------------- per-doc backward + forward finalize ----------------
__global__ __launch_bounds__(64) void k_bwd(const float* __restrict__ colsum_acc,
                                            const float* __restrict__ A_acc,
                                            const float* __restrict__ thn_f,
                                            const float* __restrict__ fwd_acc,
                                            const float* __restrict__ ntok_acc,
                                            float* __restrict__ bwd_pd,
                                            float* __restrict__ fwd_pd){
  int b = blockIdx.x, lane = threadIdx.x;
  float s = 0.f;
  for(int t = lane; t < KT; t += 64)
    s += A_acc[(long)b * KT + t] / (colsum_acc[(long)b * KT + t] + 1e-30f) * thn_f[(long)b * KT + t];
  #pragma unroll
  for(int k = 32; k >= 1; k >>= 1) s += __shfl_xor(s, k, 64);
  if(lane == 0){
    bwd_pd[b] = s;
    fwd_pd[b] = fwd_acc[b] / fmaxf(ntok_acc[b], 1.f);
  }
}

// ---------------- final reduce + 3 outputs ----------------
__global__ __launch_bounds__(512) void k_final(const float* __restrict__ bwd_pd,
                                               const float* __restrict__ fwd_pd,
                                               const float* __restrict__ ntok_acc,
                                               const float* __restrict__ tm_acc,
                                               float* __restrict__ out){
  __shared__ float rf[8], rb[8];
  int tid = threadIdx.x, w = tid >> 6, lane = tid & 63;
  bool valid = ntok_acc[tid] > 0.f;
  float fw = valid ? fwd_pd[tid] : 0.f;
  float bw = valid ? bwd_pd[tid] : 0.f;
  #pragma unroll
  for(int s = 32; s >= 1; s >>= 1){ fw += __shfl_xor(fw, s, 64); bw += __shfl_xor(bw, s, 64); }
  if(lane == 0){ rf[w] = fw; rb[w] = bw; }
  __syncthreads();
  if(tid == 0){
    float F = 0.f, Bw = 0.f;
    #pragma unroll
    for(int i = 0; i < 8; i++){ F += rf[i]; Bw += rb[i]; }
    out[0] = 1.0f * (-tm_acc[0] / (float)B_);  // EPSILON * tm
    out[1] = 0.5f * F;                         // BETA * forward
    out[2] = 0.5f * Bw;                        // (1-BETA) * backward
  }
}

extern "C" void kernel_launch(void* const* d_in, const int* in_sizes, int n_in,
                              void* d_out, int out_size, void* d_ws, size_t ws_size,
                              hipStream_t stream){
  const float* bows  = (const float*)d_in[0];
  const float* rho   = (const float*)d_in[1];
  const float* alpha = (const float*)d_in[2];
  const float* W1    = (const float*)d_in[3];
  const float* b1    = (const float*)d_in[4];
  const float* W2    = (const float*)d_in[5];
  const float* b2    = (const float*)d_in[6];
  float* out = (float*)d_out;
  char* ws = (char*)d_ws;
  size_t o = 0;
  auto alloc = [&](size_t bytes) -> char* {
    char* p = ws + o; o = (o + bytes + 255) & ~(size_t)255; return p;
  };
  // zeroed region (contiguous, zeroed every launch)
  float* hid_acc    = (float*)alloc((size_t)B_ * HIDN * 4);
  float* colsum_acc = (float*)alloc((size_t)B_ * KT * 4);
  float* A_acc      = (float*)alloc((size_t)B_ * KT * 4);
  float* sumexp     = (float*)alloc(KP * 4);
  float* fwd_acc    = (float*)alloc(B_ * 4);
  float* ntok_acc   = (float*)alloc(B_ * 4);
  float* tm_acc     = (float*)alloc(256);
  float* bwd_pd     = (float*)alloc(B_ * 4);
  float* fwd_pd     = (float*)alloc(B_ * 4);
  size_t zbytes = o;
  // scratch (fully written before read)
  short* bows_b   = (short*)alloc((size_t)B_ * V_ * 2);
  short* W1b      = (short*)alloc((size_t)V_ * HIDN * 2);
  short* rho_p    = (short*)alloc((size_t)V_ * HP * 2);
  short* alpha_p  = (short*)alloc((size_t)KT * HP * 2);
  short* theta_b  = (short*)alloc((size_t)B_ * KP * 2);
  short* thetan_b = (short*)alloc((size_t)B_ * KP * 2);
  float* thetan_f = (float*)alloc((size_t)B_ * KT * 4);
  short* dis_b    = (short*)alloc((size_t)V_ * KP * 2);
  short* cd_b     = (short*)alloc((size_t)V_ * KP * 2);

  kzero<<<512, 256, 0, stream>>>((float*)ws, (long)(zbytes / 4));
  kconv<<<2048, 256, 0, stream>>>(bows, bows_b, (long)B_ * V_ / 4);
  kconv<<<2048, 256, 0, stream>>>(W1, W1b, (long)V_ * HIDN / 4);
  kconvpad<<<V_, HP, 0, stream>>>(rho, rho_p, HH, HP);
  kconvpad<<<KT, HP, 0, stream>>>(alpha, alpha_p, HH, HP);
  k_gemm1<<<dim3(4, 7, 32), 256, 0, stream>>>(bows_b, W1b, hid_acc);
  k_theta<<<B_, 256, 0, stream>>>(hid_acc, b1, W2, b2, theta_b, thetan_b, thetan_f);
  k_inner<<<dim3((V_ + 127) / 128, 4), 256, 0, stream>>>(rho_p, alpha_p, dis_b, cd_b, sumexp);
  k_consumer<<<(V_ + 63) / 64, 256, 0, stream>>>(dis_b, cd_b, theta_b, thetan_b, sumexp,
                                                 bows, fwd_acc, ntok_acc, tm_acc);
  k_colsum<<<dim3(4, 4, 48), 256, 0, stream>>>(bows_b, dis_b, cd_b, colsum_acc, A_acc);
  k_bwd<<<B_, 64, 0, stream>>>(colsum_acc, A_acc, thetan_f, fwd_acc, ntok_acc, bwd_pd, fwd_pd);
  k_final<<<1, 512, 0, stream>>>(bwd_pd, fwd_pd, ntok_acc, tm_acc, out);
}

// Round 2
// 915.053 us; speedup vs baseline: 1.2449x; 1.2449x over previous
//
#include <hip/hip_runtime.h>

#define B_    512
#define V_    50000
#define VP    50048   // padded vocab (64*782)
#define KT    200     // topics
#define HH    300     // embedding dim
#define HIDN  800     // hidden
#define KP    224     // padded topic dim (7*32)
#define HP    320     // padded embedding dim (10*32)

typedef __attribute__((ext_vector_type(4))) float  f32x4;
typedef __attribute__((ext_vector_type(8))) short  s8v;
typedef __attribute__((ext_vector_type(8))) __bf16 bf16x8;
typedef unsigned int u32;

static __device__ __forceinline__ f32x4 mfma16(s8v a, s8v b, f32x4 c){
  return __builtin_amdgcn_mfma_f32_16x16x32_bf16(
      __builtin_bit_cast(bf16x8, a), __builtin_bit_cast(bf16x8, b), c, 0, 0, 0);
}
static __device__ __forceinline__ short f2bf(float f){
  unsigned u = __float_as_uint(f);
  u = (u + 0x7fffu + ((u >> 16) & 1u)) >> 16;
  return (short)u;
}
static __device__ __forceinline__ float bf2f(short s){
  return __uint_as_float(((unsigned)(unsigned short)s) << 16);
}
// async global->LDS, 16B per lane; LDS dest = wave-uniform base + lane*16
static __device__ __forceinline__ void load_lds16(const short* g, short* lds){
  __builtin_amdgcn_global_load_lds(
      (const __attribute__((address_space(1))) u32*)g,
      (__attribute__((address_space(3))) u32*)lds, 16, 0, 0);
}

// ---------------- zero init ----------------
__global__ void kzero(float* p, long n){
  long i = blockIdx.x * (long)blockDim.x + threadIdx.x;
  long st = (long)gridDim.x * blockDim.x;
  for(; i < n; i += st) p[i] = 0.f;
}

// ---------------- bows fp32 -> bf16, rows padded V_ -> VP with zeros ----------------
__global__ void k_bows(const float* __restrict__ src, short* __restrict__ dst){
  int b = blockIdx.y;
  int c = blockIdx.x * 256 + threadIdx.x;          // chunk of 8 shorts
  if(c >= VP / 8) return;
  int v = c * 8;
  s8v o = {0,0,0,0,0,0,0,0};
  if(v + 8 <= V_){
    float4 a = *(const float4*)&src[(long)b * V_ + v];
    float4 d = *(const float4*)&src[(long)b * V_ + v + 4];
    o[0]=f2bf(a.x); o[1]=f2bf(a.y); o[2]=f2bf(a.z); o[3]=f2bf(a.w);
    o[4]=f2bf(d.x); o[5]=f2bf(d.y); o[6]=f2bf(d.z); o[7]=f2bf(d.w);
  }
  *(s8v*)&dst[(long)b * VP + v] = o;
}

// ---------------- W1 (V x HIDN fp32) -> W1t (HIDN x VP bf16, transposed) ----------------
__global__ __launch_bounds__(256) void k_transW1(const float* __restrict__ W1,
                                                 short* __restrict__ W1t){
  __shared__ float tile[32][33];
  int v0 = blockIdx.x * 32, n0 = blockIdx.y * 32;
  int tid = threadIdx.x;
  int r = tid >> 3, c4 = (tid & 7) * 4;
  float4 val = {0.f,0.f,0.f,0.f};
  int v = v0 + r;
  if(v < V_) val = *(const float4*)&W1[(long)v * HIDN + n0 + c4];
  tile[r][c4+0] = val.x; tile[r][c4+1] = val.y; tile[r][c4+2] = val.z; tile[r][c4+3] = val.w;
  __syncthreads();
  short4 o;
  o.x = f2bf(tile[c4+0][r]); o.y = f2bf(tile[c4+1][r]);
  o.z = f2bf(tile[c4+2][r]); o.w = f2bf(tile[c4+3][r]);
  *(short4*)&W1t[(long)(n0 + r) * VP + v0 + c4] = o;
}

// ---------------- fp32 -> bf16 with row padding (blockDim = kpad) ----------------
__global__ void kconvpad(const float* __restrict__ src, short* __restrict__ dst,
                         int kin, int kpad){
  int r = blockIdx.x, c = threadIdx.x;
  float v = (c < kin) ? src[(long)r * kin + c] : 0.f;
  dst[(long)r * kpad + c] = f2bf(v);
}

// ---------------- GEMM1: hid_acc += bows @ W1 (split-K, atomic) ----------------
// A = bows_b (512 x VP), B = W1t (800 x VP, k-contig rows), C = hid_acc (512x800 f32)
__global__ __launch_bounds__(256) void k_gemm1(const short* __restrict__ Ab,
                                               const short* __restrict__ Bb,
                                               float* __restrict__ Cacc){
  __shared__ short As[128 * 32];
  __shared__ short Bs[128 * 32];
  int tid = threadIdx.x, w = tid >> 6, lane = tid & 63, lm = lane & 15, q = lane >> 4;
  int m0 = blockIdx.x * 128, n0 = blockIdx.y * 128;
  long kstart = (long)blockIdx.z * 1568;
  long kend = kstart + 1568; if(kend > VP) kend = VP;
  int rsub = lane >> 2;          // 0..15 within 16-row chunk
  int kl = (lane & 3) * 8;       // shorts within 32-short row
  int rA0 = m0 + w * 16 + rsub;
  int rA1 = m0 + (w + 4) * 16 + rsub;
  int nB0 = n0 + w * 16 + rsub;       if(nB0 > HIDN - 1) nB0 = HIDN - 1;
  int nB1 = n0 + (w + 4) * 16 + rsub; if(nB1 > HIDN - 1) nB1 = HIDN - 1;
  f32x4 acc[2][8];
  #pragma unroll
  for(int i = 0; i < 2; i++)
    #pragma unroll
    for(int j = 0; j < 8; j++) acc[i][j] = (f32x4){0.f,0.f,0.f,0.f};

  for(long kb = kstart; kb < kend; kb += 32){
    load_lds16(&Ab[(long)rA0 * VP + kb + kl], &As[w * 512]);
    load_lds16(&Ab[(long)rA1 * VP + kb + kl], &As[(w + 4) * 512]);
    load_lds16(&Bb[(long)nB0 * VP + kb + kl], &Bs[w * 512]);
    load_lds16(&Bb[(long)nB1 * VP + kb + kl], &Bs[(w + 4) * 512]);
    __syncthreads();
    s8v af[2], bfr[8];
    #pragma unroll
    for(int i = 0; i < 2; i++) af[i]  = *(const s8v*)&As[(w * 32 + i * 16 + lm) * 32 + q * 8];
    #pragma unroll
    for(int j = 0; j < 8; j++) bfr[j] = *(const s8v*)&Bs[(j * 16 + lm) * 32 + q * 8];
    #pragma unroll
    for(int i = 0; i < 2; i++)
      #pragma unroll
      for(int j = 0; j < 8; j++)
        acc[i][j] = mfma16(af[i], bfr[j], acc[i][j]);
    __syncthreads();
  }
  #pragma unroll
  for(int i = 0; i < 2; i++)
    #pragma unroll
    for(int j = 0; j < 8; j++){
      int gm = m0 + w * 32 + i * 16 + q * 4;
      int gn = n0 + j * 16 + lm;
      if(gn < HIDN){
        #pragma unroll
        for(int r = 0; r < 4; r++) atomicAdd(&Cacc[(long)(gm + r) * HIDN + gn], acc[i][j][r]);
      }
    }
}

// ---------------- theta: relu(hid+b1) @ W2 + b2 -> softplus -> softmax ----------------
__global__ __launch_bounds__(256) void k_theta(const float* __restrict__ hid_acc,
                                               const float* __restrict__ b1,
                                               const float* __restrict__ W2,
                                               const float* __restrict__ b2,
                                               short* __restrict__ theta_b,
                                               short* __restrict__ thetan_b,
                                               float* __restrict__ thetan_f){
  __shared__ float hrow[HIDN];
  __shared__ float thl[256];
  __shared__ float redm[4], reds[4];
  int b = blockIdx.x, tid = threadIdx.x;
  for(int h = tid; h < HIDN; h += 256){
    float x = hid_acc[(long)b * HIDN + h] + b1[h];
    hrow[h] = x > 0.f ? x : 0.f;
  }
  __syncthreads();
  float th = 0.f;
  if(tid < KT){
    float z = b2[tid];
    #pragma unroll 4
    for(int h = 0; h < HIDN; h++) z += hrow[h] * W2[h * KT + tid];
    th = (z > 0.f ? z : 0.f) + log1pf(expf(-fabsf(z)));   // softplus
  }
  thl[tid] = (tid < KT) ? th : -1e30f;
  __syncthreads();
  float m = thl[tid];
  #pragma unroll
  for(int s = 32; s >= 1; s >>= 1) m = fmaxf(m, __shfl_xor(m, s, 64));
  if((tid & 63) == 0) redm[tid >> 6] = m;
  __syncthreads();
  float mx = fmaxf(fmaxf(redm[0], redm[1]), fmaxf(redm[2], redm[3]));
  float e = (tid < KT) ? expf(th - mx) : 0.f;
  float s_ = e;
  #pragma unroll
  for(int s = 32; s >= 1; s >>= 1) s_ += __shfl_xor(s_, s, 64);
  if((tid & 63) == 0) reds[tid >> 6] = s_;
  __syncthreads();
  float sum = reds[0] + reds[1] + reds[2] + reds[3];
  if(tid < KP){
    short tb  = (tid < KT) ? f2bf(th) : (short)0;
    short tnb = (tid < KT) ? f2bf(e / sum) : (short)0;
    theta_b [(long)b * KP + tid] = tb;
    thetan_b[(long)b * KP + tid] = tnb;
  }
  if(tid < KT) thetan_f[(long)b * KT + tid] = e / sum;
}

// ---------------- inner = rho @ alpha^T ; write dis_t, cd_t (topic-major KP x VP), sumexp ----------------
__global__ __launch_bounds__(256) void k_inner(const short* __restrict__ rho_p,
                                               const short* __restrict__ alpha_p,
                                               short* __restrict__ dis_t,
                                               short* __restrict__ cd_t,
                                               float* __restrict__ sumexp){
  __shared__ short As[128 * 40];
  __shared__ short Bs[64 * 40];
  __shared__ short tDis[128 * 72];
  __shared__ short tCd [128 * 72];
  __shared__ float sume_l[64];
  int tid = threadIdx.x, w = tid >> 6, lane = tid & 63, lm = lane & 15, q = lane >> 4;
  int v0 = blockIdx.x * 128, t0 = blockIdx.y * 64;
  if(tid < 64) sume_l[tid] = 0.f;
  __syncthreads();
  f32x4 acc[2][4];
  #pragma unroll
  for(int i = 0; i < 2; i++)
    #pragma unroll
    for(int j = 0; j < 4; j++) acc[i][j] = (f32x4){0.f,0.f,0.f,0.f};

  for(int h0 = 0; h0 < HP; h0 += 32){
    #pragma unroll
    for(int c0 = 0; c0 < 2; c0++){
      int c = tid + c0 * 256;
      int r = c >> 2, off = (c & 3) * 8;
      int vg = v0 + r;
      s8v v = {0,0,0,0,0,0,0,0};
      if(vg < V_) v = *(const s8v*)&rho_p[(long)vg * HP + h0 + off];
      *(s8v*)&As[r * 40 + off] = v;
    }
    {
      int r = tid >> 2, off = (tid & 3) * 8;
      int tg = t0 + r;
      s8v v = {0,0,0,0,0,0,0,0};
      if(tg < KT) v = *(const s8v*)&alpha_p[(long)tg * HP + h0 + off];
      *(s8v*)&Bs[r * 40 + off] = v;
    }
    __syncthreads();
    s8v af[2], bfr[4];
    #pragma unroll
    for(int i = 0; i < 2; i++) af[i]  = *(const s8v*)&As[(w * 32 + i * 16 + lm) * 40 + q * 8];
    #pragma unroll
    for(int j = 0; j < 4; j++) bfr[j] = *(const s8v*)&Bs[(j * 16 + lm) * 40 + q * 8];
    #pragma unroll
    for(int i = 0; i < 2; i++)
      #pragma unroll
      for(int j = 0; j < 4; j++)
        acc[i][j] = mfma16(af[i], bfr[j], acc[i][j]);
    __syncthreads();
  }
  // epilogue: dis/cd into LDS tile (v-major, padded stride) + per-t exp sums
  #pragma unroll
  for(int i = 0; i < 2; i++)
    #pragma unroll
    for(int j = 0; j < 4; j++){
      int tg = t0 + j * 16 + lm;
      float s4 = 0.f;
      #pragma unroll
      for(int r = 0; r < 4; r++){
        int vloc = w * 32 + i * 16 + q * 4 + r;
        int vg = v0 + vloc;
        float x = acc[i][j][r];
        float e1 = __expf(x);  e1 = fminf(fmaxf(e1, 1e-30f), 1e10f);
        float e2 = __expf(-x); e2 = fminf(fmaxf(e2, 1e-30f), 1e10f);
        float cd = e1 * e2;
        bool valid = (vg < V_) && (tg < KT);
        float dv = valid ? e1 : 0.f;
        float cv = valid ? cd : 0.f;
        tDis[vloc * 72 + (j * 16 + lm)] = f2bf(dv);
        tCd [vloc * 72 + (j * 16 + lm)] = f2bf(cv);
        s4 += dv;
      }
      s4 += __shfl_xor(s4, 16, 64);
      s4 += __shfl_xor(s4, 32, 64);
      if(q == 0) atomicAdd(&sume_l[j * 16 + lm], s4);
    }
  __syncthreads();
  // write out topic-major: dis_t[t][v], 16B contiguous in v
  for(int c = tid; c < 1024; c += 256){
    int t = c & 63, vch = c >> 6;          // vch 0..15
    int tg = t0 + t;
    if(tg < KP){
      s8v d, cc;
      #pragma unroll
      for(int j = 0; j < 8; j++){
        d[j]  = tDis[(vch * 8 + j) * 72 + t];
        cc[j] = tCd [(vch * 8 + j) * 72 + t];
      }
      *(s8v*)&dis_t[(long)tg * VP + v0 + vch * 8] = d;
      *(s8v*)&cd_t [(long)tg * VP + v0 + vch * 8] = cc;
    }
  }
  if(tid < 64 && (t0 + tid) < KT) atomicAdd(&sumexp[t0 + tid], sume_l[tid]);
}

// ---------------- fused consumer: num/den/recon GEMMs + forward/ntok/tm reductions ----------------
#define TSTR 232   // LDS topic stride (shorts), 8-aligned for b128
__global__ __launch_bounds__(256) void k_consumer(const short* __restrict__ dis_t,
                                                  const short* __restrict__ cd_t,
                                                  const short* __restrict__ theta_b,
                                                  const short* __restrict__ thetan_b,
                                                  const float* __restrict__ sumexp,
                                                  const short* __restrict__ bows_b,
                                                  float* __restrict__ fwd_acc,
                                                  float* __restrict__ ntok_acc,
                                                  float* __restrict__ tm_acc){
  __shared__ short tD[64 * TSTR];
  __shared__ short tC[64 * TSTR];
  __shared__ float fwd_l[B_];
  __shared__ float ntok_l[B_];
  __shared__ float tm_l;
  int tid = threadIdx.x;
  for(int i = tid; i < B_; i += 256){ fwd_l[i] = 0.f; ntok_l[i] = 0.f; }
  if(tid == 0) tm_l = 0.f;
  int v0 = blockIdx.x * 64;
  // stage 64v x 224t tiles of dis/cd, transposed to v-major in LDS
  for(int c = tid; c < KP * 8; c += 256){   // 1792 = 7 iters
    int t = c >> 3, vch = c & 7;
    s8v d  = *(const s8v*)&dis_t[(long)t * VP + v0 + vch * 8];
    s8v cc = *(const s8v*)&cd_t [(long)t * VP + v0 + vch * 8];
    #pragma unroll
    for(int j = 0; j < 8; j++){
      tD[(vch * 8 + j) * TSTR + t] = d[j];
      tC[(vch * 8 + j) * TSTR + t] = cc[j];
    }
  }
  __syncthreads();
  int w = tid >> 6, lane = tid & 63, lm = lane & 15, q = lane >> 4;
  int vloc = w * 16 + lm;
  s8v disf[7], cdf[7], phif[7];
  #pragma unroll
  for(int i = 0; i < 7; i++){
    int tc = i * 32 + q * 8;
    disf[i] = *(const s8v*)&tD[vloc * TSTR + tc];
    cdf[i]  = *(const s8v*)&tC[vloc * TSTR + tc];
    s8v p;
    #pragma unroll
    for(int j = 0; j < 8; j++){
      int t = tc + j;
      float se = (t < KT) ? sumexp[t] : 1.f;
      p[j] = f2bf(bf2f(disf[i][j]) / se);
    }
    phif[i] = p;
  }

  float tmreg = 0.f;
  for(int cb = 0; cb < 32; cb++){
    int b0 = cb * 16;
    f32x4 aN = {0.f,0.f,0.f,0.f}, aD = {0.f,0.f,0.f,0.f}, aR = {0.f,0.f,0.f,0.f};
    #pragma unroll
    for(int i = 0; i < 7; i++){
      long off = (long)(b0 + lm) * KP + i * 32 + q * 8;
      s8v tn = *(const s8v*)&thetan_b[off];
      s8v tt = *(const s8v*)&theta_b[off];
      aD = mfma16(disf[i], tn, aD);
      aN = mfma16(cdf[i],  tn, aN);
      aR = mfma16(phif[i], tt, aR);
    }
    int bg = b0 + lm;
    short4 bw4 = *(const short4*)&bows_b[(long)bg * VP + v0 + w * 16 + q * 4];
    float bvv[4] = {bf2f(bw4.x), bf2f(bw4.y), bf2f(bw4.z), bf2f(bw4.w)};
    float fwd_p = 0.f, nt_p = 0.f;
    #pragma unroll
    for(int r = 0; r < 4; r++){
      float den = aD[r] + 1e-30f;
      float f = aN[r] / den;
      float rec = aR[r];
      float bv = bvv[r];
      fwd_p += bv * f;
      nt_p  += bv;
      float lg = bv < 1.5f ? 0.f : (bv < 2.5f ? 0.69314718056f :
                 (bv < 3.5f ? 1.79175946923f : 3.17805383035f));
      tmreg += bv * __logf(rec + 1e-10f) - rec - lg;
    }
    fwd_p += __shfl_xor(fwd_p, 16, 64); fwd_p += __shfl_xor(fwd_p, 32, 64);
    nt_p  += __shfl_xor(nt_p, 16, 64);  nt_p  += __shfl_xor(nt_p, 32, 64);
    if(q == 0){
      atomicAdd(&fwd_l[bg], fwd_p);
      atomicAdd(&ntok_l[bg], nt_p);
    }
  }
  #pragma unroll
  for(int s = 32; s >= 1; s >>= 1) tmreg += __shfl_xor(tmreg, s, 64);
  if(lane == 0) atomicAdd(&tm_l, tmreg);
  __syncthreads();
  for(int i = tid; i < B_; i += 256){
    atomicAdd(&fwd_acc[i], fwd_l[i]);
    atomicAdd(&ntok_acc[i], ntok_l[i]);
  }
  if(tid == 0) atomicAdd(tm_acc, tm_l);
}

// ---------------- colsum = bows@dis, A = bows@cd (split-K, atomic) ----------------
// A = bows_b (512 x VP), B = dis_t/cd_t (KP x VP, topic-major k-contig rows)
__global__ __launch_bounds__(256) void k_colsum(const short* __restrict__ bows_b,
                                                const short* __restrict__ dis_t,
                                                const short* __restrict__ cd_t,
                                                float* __restrict__ colsum_acc,
                                                float* __restrict__ A_acc){
  __shared__ short As[128 * 32];
  __shared__ short BsD[64 * 32];
  __shared__ short BsC[64 * 32];
  int tid = threadIdx.x, w = tid >> 6, lane = tid & 63, lm = lane & 15, q = lane >> 4;
  int m0 = blockIdx.x * 128, t0 = blockIdx.y * 64;
  long kstart = (long)blockIdx.z * 2112;
  long kend = kstart + 2112; if(kend > VP) kend = VP;
  int rsub = lane >> 2;
  int kl = (lane & 3) * 8;
  int rA0 = m0 + w * 16 + rsub;
  int rA1 = m0 + (w + 4) * 16 + rsub;
  int tB = t0 + w * 16 + rsub; if(tB > KP - 1) tB = KP - 1;   // rows >= KT are zeros
  f32x4 accD[2][4], accC[2][4];
  #pragma unroll
  for(int i = 0; i < 2; i++)
    #pragma unroll
    for(int j = 0; j < 4; j++){ accD[i][j] = (f32x4){0.f,0.f,0.f,0.f}; accC[i][j] = (f32x4){0.f,0.f,0.f,0.f}; }

  for(long kb = kstart; kb < kend; kb += 32){
    load_lds16(&bows_b[(long)rA0 * VP + kb + kl], &As[w * 512]);
    load_lds16(&bows_b[(long)rA1 * VP + kb + kl], &As[(w + 4) * 512]);
    load_lds16(&dis_t[(long)tB * VP + kb + kl], &BsD[w * 512]);
    load_lds16(&cd_t [(long)tB * VP + kb + kl], &BsC[w * 512]);
    __syncthreads();
    s8v af[2], bd[4], bc[4];
    #pragma unroll
    for(int i = 0; i < 2; i++) af[i] = *(const s8v*)&As[(w * 32 + i * 16 + lm) * 32 + q * 8];
    #pragma unroll
    for(int j = 0; j < 4; j++){
      bd[j] = *(const s8v*)&BsD[(j * 16 + lm) * 32 + q * 8];
      bc[j] = *(const s8v*)&BsC[(j * 16 + lm) * 32 + q * 8];
    }
    #pragma unroll
    for(int i = 0; i < 2; i++)
      #pragma unroll
      for(int j = 0; j < 4; j++){
        accD[i][j] = mfma16(af[i], bd[j], accD[i][j]);
        accC[i][j] = mfma16(af[i], bc[j], accC[i][j]);
      }
    __syncthreads();
  }
  #pragma unroll
  for(int i = 0; i < 2; i++)
    #pragma unroll
    for(int j = 0; j < 4; j++){
      int doc = m0 + w * 32 + i * 16 + q * 4;
      int tg = t0 + j * 16 + lm;
      if(tg < KT){
        #pragma unroll
        for(int r = 0; r < 4; r++){
          atomicAdd(&colsum_acc[(long)(doc + r) * KT + tg], accD[i][j][r]);
          atomicAdd(&A_acc     [(long)(doc + r) * KT + tg], accC[i][j][r]);
        }
      }
    }
}

// ---------------- per-doc backward + forward finalize ----------------
__global__ __launch_bounds__(64) void k_bwd(const float* __restrict__ colsum_acc,
                                            const float* __restrict__ A_acc,
                                            const float* __restrict__ thn_f,
                                            const float* __restrict__ fwd_acc,
                                            const float* __restrict__ ntok_acc,
                                            float* __restrict__ bwd_pd,
                                            float* __restrict__ fwd_pd){
  int b = blockIdx.x, lane = threadIdx.x;
  float s = 0.f;
  for(int t = lane; t < KT; t += 64)
    s += A_acc[(long)b * KT + t] / (colsum_acc[(long)b * KT + t] + 1e-30f) * thn_f[(long)b * KT + t];
  #pragma unroll
  for(int k = 32; k >= 1; k >>= 1) s += __shfl_xor(s, k, 64);
  if(lane == 0){
    bwd_pd[b] = s;
    fwd_pd[b] = fwd_acc[b] / fmaxf(ntok_acc[b], 1.f);
  }
}

// ---------------- final reduce + 3 outputs ----------------
__global__ __launch_bounds__(512) void k_final(const float* __restrict__ bwd_pd,
                                               const float* __restrict__ fwd_pd,
                                               const float* __restrict__ ntok_acc,
                                               const float* __restrict__ tm_acc,
                                               float* __restrict__ out){
  __shared__ float rf[8], rb[8];
  int tid = threadIdx.x, w = tid >> 6, lane = tid & 63;
  bool valid = ntok_acc[tid] > 0.f;
  float fw = valid ? fwd_pd[tid] : 0.f;
  float bw = valid ? bwd_pd[tid] : 0.f;
  #pragma unroll
  for(int s = 32; s >= 1; s >>= 1){ fw += __shfl_xor(fw, s, 64); bw += __shfl_xor(bw, s, 64); }
  if(lane == 0){ rf[w] = fw; rb[w] = bw; }
  __syncthreads();
  if(tid == 0){
    float F = 0.f, Bw = 0.f;
    #pragma unroll
    for(int i = 0; i < 8; i++){ F += rf[i]; Bw += rb[i]; }
    out[0] = 1.0f * (-tm_acc[0] / (float)B_);  // EPSILON * tm
    out[1] = 0.5f * F;                         // BETA * forward
    out[2] = 0.5f * Bw;                        // (1-BETA) * backward
  }
}

extern "C" void kernel_launch(void* const* d_in, const int* in_sizes, int n_in,
                              void* d_out, int out_size, void* d_ws, size_t ws_size,
                              hipStream_t stream){
  const float* bows  = (const float*)d_in[0];
  const float* rho   = (const float*)d_in[1];
  const float* alpha = (const float*)d_in[2];
  const float* W1    = (const float*)d_in[3];
  const float* b1    = (const float*)d_in[4];
  const float* W2    = (const float*)d_in[5];
  const float* b2    = (const float*)d_in[6];
  float* out = (float*)d_out;
  char* ws = (char*)d_ws;
  size_t o = 0;
  auto alloc = [&](size_t bytes) -> char* {
    char* p = ws + o; o = (o + bytes + 255) & ~(size_t)255; return p;
  };
  // zeroed region (contiguous, zeroed every launch)
  float* hid_acc    = (float*)alloc((size_t)B_ * HIDN * 4);
  float* colsum_acc = (float*)alloc((size_t)B_ * KT * 4);
  float* A_acc      = (float*)alloc((size_t)B_ * KT * 4);
  float* sumexp     = (float*)alloc(KP * 4);
  float* fwd_acc    = (float*)alloc(B_ * 4);
  float* ntok_acc   = (float*)alloc(B_ * 4);
  float* tm_acc     = (float*)alloc(256);
  float* bwd_pd     = (float*)alloc(B_ * 4);
  float* fwd_pd     = (float*)alloc(B_ * 4);
  size_t zbytes = o;
  // scratch (fully written before read)
  short* bows_b   = (short*)alloc((size_t)B_ * VP * 2);
  short* W1t      = (short*)alloc((size_t)HIDN * VP * 2);
  short* rho_p    = (short*)alloc((size_t)V_ * HP * 2);
  short* alpha_p  = (short*)alloc((size_t)KT * HP * 2);
  short* theta_b  = (short*)alloc((size_t)B_ * KP * 2);
  short* thetan_b = (short*)alloc((size_t)B_ * KP * 2);
  float* thetan_f = (float*)alloc((size_t)B_ * KT * 4);
  short* dis_t    = (short*)alloc((size_t)KP * VP * 2);
  short* cd_t     = (short*)alloc((size_t)KP * VP * 2);

  kzero<<<256, 256, 0, stream>>>((float*)ws, (long)(zbytes / 4));
  k_bows<<<dim3(25, 512), 256, 0, stream>>>(bows, bows_b);
  k_transW1<<<dim3(VP / 32, HIDN / 32), 256, 0, stream>>>(W1, W1t);
  kconvpad<<<V_, HP, 0, stream>>>(rho, rho_p, HH, HP);
  kconvpad<<<KT, HP, 0, stream>>>(alpha, alpha_p, HH, HP);
  k_gemm1<<<dim3(4, 7, 32), 256, 0, stream>>>(bows_b, W1t, hid_acc);
  k_theta<<<B_, 256, 0, stream>>>(hid_acc, b1, W2, b2, theta_b, thetan_b, thetan_f);
  k_inner<<<dim3(VP / 128, 4), 256, 0, stream>>>(rho_p, alpha_p, dis_t, cd_t, sumexp);
  k_consumer<<<VP / 64, 256, 0, stream>>>(dis_t, cd_t, theta_b, thetan_b, sumexp,
                                          bows_b, fwd_acc, ntok_acc, tm_acc);
  k_colsum<<<dim3(4, 4, 24), 256, 0, stream>>>(bows_b, dis_t, cd_t, colsum_acc, A_acc);
  k_bwd<<<B_, 64, 0, stream>>>(colsum_acc, A_acc, thetan_f, fwd_acc, ntok_acc, bwd_pd, fwd_pd);
  k_final<<<1, 512, 0, stream>>>(bwd_pd, fwd_pd, ntok_acc, tm_acc, out);
}

// Round 4
// 835.920 us; speedup vs baseline: 1.3628x; 1.0947x over previous
//
#include <hip/hip_runtime.h>

#define B_    512
#define V_    50000
#define VP    50048   // padded vocab (64*782)
#define KT    200     // topics
#define HH    300     // embedding dim
#define HIDN  800     // hidden
#define KP    224     // padded topic dim (7*32)
#define HP    320     // padded embedding dim (10*32)

typedef __attribute__((ext_vector_type(4))) float  f32x4;
typedef __attribute__((ext_vector_type(8))) short  s8v;
typedef __attribute__((ext_vector_type(8))) __bf16 bf16x8;
typedef unsigned int u32;

static __device__ __forceinline__ f32x4 mfma16(s8v a, s8v b, f32x4 c){
  return __builtin_amdgcn_mfma_f32_16x16x32_bf16(
      __builtin_bit_cast(bf16x8, a), __builtin_bit_cast(bf16x8, b), c, 0, 0, 0);
}
static __device__ __forceinline__ short f2bf(float f){
  unsigned u = __float_as_uint(f);
  u = (u + 0x7fffu + ((u >> 16) & 1u)) >> 16;
  return (short)u;
}
// async global->LDS, 16B per lane; LDS dest = wave-uniform base + lane*16
static __device__ __forceinline__ void load_lds16(const short* g, short* lds){
  __builtin_amdgcn_global_load_lds(
      (const __attribute__((address_space(1))) u32*)g,
      (__attribute__((address_space(3))) u32*)lds, 16, 0, 0);
}

// ---------------- zero init ----------------
__global__ void kzero(float* p, long n){
  long i = blockIdx.x * (long)blockDim.x + threadIdx.x;
  long st = (long)gridDim.x * blockDim.x;
  for(; i < n; i += st) p[i] = 0.f;
}

// ---------------- bows fp32 -> bf16 (rows padded to VP) + per-doc token counts ----------------
__global__ __launch_bounds__(256) void k_bows(const float* __restrict__ src,
                                              short* __restrict__ dst,
                                              float* __restrict__ ntok_acc){
  __shared__ float r4[4];
  int b = blockIdx.y;
  int c = blockIdx.x * 256 + threadIdx.x;          // chunk of 8 shorts
  int lane = threadIdx.x & 63, w = threadIdx.x >> 6;
  float s = 0.f;
  if(c < VP / 8){
    int v = c * 8;
    s8v o = {0,0,0,0,0,0,0,0};
    if(v + 8 <= V_){
      float4 a = *(const float4*)&src[(long)b * V_ + v];
      float4 d = *(const float4*)&src[(long)b * V_ + v + 4];
      o[0]=f2bf(a.x); o[1]=f2bf(a.y); o[2]=f2bf(a.z); o[3]=f2bf(a.w);
      o[4]=f2bf(d.x); o[5]=f2bf(d.y); o[6]=f2bf(d.z); o[7]=f2bf(d.w);
      s = a.x + a.y + a.z + a.w + d.x + d.y + d.z + d.w;
    }
    *(s8v*)&dst[(long)b * VP + v] = o;
  }
  #pragma unroll
  for(int k = 32; k >= 1; k >>= 1) s += __shfl_xor(s, k, 64);
  if(lane == 0) r4[w] = s;
  __syncthreads();
  if(threadIdx.x == 0) atomicAdd(&ntok_acc[b], r4[0] + r4[1] + r4[2] + r4[3]);
}

// ---------------- W1 (V x HIDN fp32) -> W1t (HIDN x VP bf16, transposed) ----------------
__global__ __launch_bounds__(256) void k_transW1(const float* __restrict__ W1,
                                                 short* __restrict__ W1t){
  __shared__ float tile[32][33];
  int v0 = blockIdx.x * 32, n0 = blockIdx.y * 32;
  int tid = threadIdx.x;
  int r = tid >> 3, c4 = (tid & 7) * 4;
  float4 val = {0.f,0.f,0.f,0.f};
  int v = v0 + r;
  if(v < V_) val = *(const float4*)&W1[(long)v * HIDN + n0 + c4];
  tile[r][c4+0] = val.x; tile[r][c4+1] = val.y; tile[r][c4+2] = val.z; tile[r][c4+3] = val.w;
  __syncthreads();
  short4 o;
  o.x = f2bf(tile[c4+0][r]); o.y = f2bf(tile[c4+1][r]);
  o.z = f2bf(tile[c4+2][r]); o.w = f2bf(tile[c4+3][r]);
  *(short4*)&W1t[(long)(n0 + r) * VP + v0 + c4] = o;
}

// ---------------- fp32 -> bf16 with row padding (blockDim = kpad) ----------------
__global__ void kconvpad(const float* __restrict__ src, short* __restrict__ dst,
                         int kin, int kpad){
  int r = blockIdx.x, c = threadIdx.x;
  float v = (c < kin) ? src[(long)r * kin + c] : 0.f;
  dst[(long)r * kpad + c] = f2bf(v);
}

// ---------------- GEMM1: hid_acc += bows @ W1 (split-K, atomic) ----------------
__global__ __launch_bounds__(256) void k_gemm1(const short* __restrict__ Ab,
                                               const short* __restrict__ Bb,
                                               float* __restrict__ Cacc){
  __shared__ short As[128 * 32];
  __shared__ short Bs[128 * 32];
  int tid = threadIdx.x, w = tid >> 6, lane = tid & 63, lm = lane & 15, q = lane >> 4;
  int m0 = blockIdx.x * 128, n0 = blockIdx.y * 128;
  long kstart = (long)blockIdx.z * 1568;
  long kend = kstart + 1568; if(kend > VP) kend = VP;
  int rsub = lane >> 2;          // 0..15 within 16-row chunk
  int kl = (lane & 3) * 8;       // shorts within 32-short row
  int rA0 = m0 + w * 16 + rsub;
  int rA1 = m0 + (w + 4) * 16 + rsub;
  int nB0 = n0 + w * 16 + rsub;       if(nB0 > HIDN - 1) nB0 = HIDN - 1;
  int nB1 = n0 + (w + 4) * 16 + rsub; if(nB1 > HIDN - 1) nB1 = HIDN - 1;
  f32x4 acc[2][8];
  #pragma unroll
  for(int i = 0; i < 2; i++)
    #pragma unroll
    for(int j = 0; j < 8; j++) acc[i][j] = (f32x4){0.f,0.f,0.f,0.f};

  for(long kb = kstart; kb < kend; kb += 32){
    load_lds16(&Ab[(long)rA0 * VP + kb + kl], &As[w * 512]);
    load_lds16(&Ab[(long)rA1 * VP + kb + kl], &As[(w + 4) * 512]);
    load_lds16(&Bb[(long)nB0 * VP + kb + kl], &Bs[w * 512]);
    load_lds16(&Bb[(long)nB1 * VP + kb + kl], &Bs[(w + 4) * 512]);
    __syncthreads();
    s8v af[2], bfr[8];
    #pragma unroll
    for(int i = 0; i < 2; i++) af[i]  = *(const s8v*)&As[(w * 32 + i * 16 + lm) * 32 + q * 8];
    #pragma unroll
    for(int j = 0; j < 8; j++) bfr[j] = *(const s8v*)&Bs[(j * 16 + lm) * 32 + q * 8];
    #pragma unroll
    for(int i = 0; i < 2; i++)
      #pragma unroll
      for(int j = 0; j < 8; j++)
        acc[i][j] = mfma16(af[i], bfr[j], acc[i][j]);
    __syncthreads();
  }
  #pragma unroll
  for(int i = 0; i < 2; i++)
    #pragma unroll
    for(int j = 0; j < 8; j++){
      int gm = m0 + w * 32 + i * 16 + q * 4;
      int gn = n0 + j * 16 + lm;
      if(gn < HIDN){
        #pragma unroll
        for(int r = 0; r < 4; r++) atomicAdd(&Cacc[(long)(gm + r) * HIDN + gn], acc[i][j][r]);
      }
    }
}

// ---------------- theta: relu(hid+b1) @ W2 + b2 -> softplus -> softmax / scaled ----------------
__global__ __launch_bounds__(256) void k_theta(const float* __restrict__ hid_acc,
                                               const float* __restrict__ b1,
                                               const float* __restrict__ W2,
                                               const float* __restrict__ b2,
                                               const float* __restrict__ sumexp,
                                               short* __restrict__ thetas_b,
                                               short* __restrict__ thetan_b,
                                               float* __restrict__ thetan_f){
  __shared__ float hrow[HIDN];
  __shared__ float thl[256];
  __shared__ float redm[4], reds[4];
  int b = blockIdx.x, tid = threadIdx.x;
  for(int h = tid; h < HIDN; h += 256){
    float x = hid_acc[(long)b * HIDN + h] + b1[h];
    hrow[h] = x > 0.f ? x : 0.f;
  }
  __syncthreads();
  float th = 0.f;
  if(tid < KT){
    float z = b2[tid];
    #pragma unroll 4
    for(int h = 0; h < HIDN; h++) z += hrow[h] * W2[h * KT + tid];
    th = (z > 0.f ? z : 0.f) + log1pf(expf(-fabsf(z)));   // softplus
  }
  thl[tid] = (tid < KT) ? th : -1e30f;
  __syncthreads();
  float m = thl[tid];
  #pragma unroll
  for(int s = 32; s >= 1; s >>= 1) m = fmaxf(m, __shfl_xor(m, s, 64));
  if((tid & 63) == 0) redm[tid >> 6] = m;
  __syncthreads();
  float mx = fmaxf(fmaxf(redm[0], redm[1]), fmaxf(redm[2], redm[3]));
  float e = (tid < KT) ? expf(th - mx) : 0.f;
  float s_ = e;
  #pragma unroll
  for(int s = 32; s >= 1; s >>= 1) s_ += __shfl_xor(s_, s, 64);
  if((tid & 63) == 0) reds[tid >> 6] = s_;
  __syncthreads();
  float sum = reds[0] + reds[1] + reds[2] + reds[3];
  if(tid < KP){
    short ts  = (tid < KT) ? f2bf(th / sumexp[tid]) : (short)0;  // theta / sum_v dis
    short tnb = (tid < KT) ? f2bf(e / sum) : (short)0;
    thetas_b[(long)b * KP + tid] = ts;
    thetan_b[(long)b * KP + tid] = tnb;
  }
  if(tid < KT) thetan_f[(long)b * KT + tid] = e / sum;
}

// ---------------- inner = rho @ alpha^T ; dis in topic-major (dis_t) + v-major (dis_v); sumexp ----------------
__global__ __launch_bounds__(256) void k_inner(const short* __restrict__ rho_p,
                                               const short* __restrict__ alpha_p,
                                               short* __restrict__ dis_t,
                                               short* __restrict__ dis_v,
                                               float* __restrict__ sumexp){
  __shared__ short As[128 * 40];
  __shared__ short Bs[64 * 40];
  __shared__ short tDis[128 * 72];
  __shared__ float sume_l[64];
  int tid = threadIdx.x, w = tid >> 6, lane = tid & 63, lm = lane & 15, q = lane >> 4;
  int v0 = blockIdx.x * 128, t0 = blockIdx.y * 64;
  if(tid < 64) sume_l[tid] = 0.f;
  __syncthreads();
  f32x4 acc[2][4];
  #pragma unroll
  for(int i = 0; i < 2; i++)
    #pragma unroll
    for(int j = 0; j < 4; j++) acc[i][j] = (f32x4){0.f,0.f,0.f,0.f};

  for(int h0 = 0; h0 < HP; h0 += 32){
    #pragma unroll
    for(int c0 = 0; c0 < 2; c0++){
      int c = tid + c0 * 256;
      int r = c >> 2, off = (c & 3) * 8;
      int vg = v0 + r;
      s8v v = {0,0,0,0,0,0,0,0};
      if(vg < V_) v = *(const s8v*)&rho_p[(long)vg * HP + h0 + off];
      *(s8v*)&As[r * 40 + off] = v;
    }
    {
      int r = tid >> 2, off = (tid & 3) * 8;
      int tg = t0 + r;
      s8v v = {0,0,0,0,0,0,0,0};
      if(tg < KT) v = *(const s8v*)&alpha_p[(long)tg * HP + h0 + off];
      *(s8v*)&Bs[r * 40 + off] = v;
    }
    __syncthreads();
    s8v af[2], bfr[4];
    #pragma unroll
    for(int i = 0; i < 2; i++) af[i]  = *(const s8v*)&As[(w * 32 + i * 16 + lm) * 40 + q * 8];
    #pragma unroll
    for(int j = 0; j < 4; j++) bfr[j] = *(const s8v*)&Bs[(j * 16 + lm) * 40 + q * 8];
    #pragma unroll
    for(int i = 0; i < 2; i++)
      #pragma unroll
      for(int j = 0; j < 4; j++)
        acc[i][j] = mfma16(af[i], bfr[j], acc[i][j]);
    __syncthreads();
  }
  // epilogue: dis into LDS tile (v-major, padded stride) + per-t exp sums
  #pragma unroll
  for(int i = 0; i < 2; i++)
    #pragma unroll
    for(int j = 0; j < 4; j++){
      int tg = t0 + j * 16 + lm;
      float s4 = 0.f;
      #pragma unroll
      for(int r = 0; r < 4; r++){
        int vloc = w * 32 + i * 16 + q * 4 + r;
        int vg = v0 + vloc;
        float x = acc[i][j][r];
        float e1 = __expf(x);  e1 = fminf(fmaxf(e1, 1e-30f), 1e10f);
        bool valid = (vg < V_) && (tg < KT);
        float dv = valid ? e1 : 0.f;
        tDis[vloc * 72 + (j * 16 + lm)] = f2bf(dv);
        s4 += dv;
      }
      s4 += __shfl_xor(s4, 16, 64);
      s4 += __shfl_xor(s4, 32, 64);
      if(q == 0) atomicAdd(&sume_l[j * 16 + lm], s4);
    }
  __syncthreads();
  // topic-major: dis_t[t][v], 16B contiguous in v  (guard: rows >= KP don't exist)
  for(int c = tid; c < 1024; c += 256){
    int t = c & 63, vch = c >> 6;          // vch 0..15
    int tg = t0 + t;
    if(tg < KP){
      s8v d;
      #pragma unroll
      for(int j = 0; j < 8; j++) d[j] = tDis[(vch * 8 + j) * 72 + t];
      *(s8v*)&dis_t[(long)tg * VP + v0 + vch * 8] = d;
    }
  }
  // v-major: dis_v[v][t], 16B contiguous in t  (guard: t0=192 block only owns cols 192..223)
  for(int c = tid; c < 1024; c += 256){
    int r = c >> 3, tch = (c & 7) * 8;     // r 0..127, tch 0..56
    if(t0 + tch < KP)
      *(s8v*)&dis_v[(long)(v0 + r) * KP + t0 + tch] = *(const s8v*)&tDis[r * 72 + tch];
  }
  if(tid < 64 && (t0 + tid) < KT) atomicAdd(&sumexp[t0 + tid], sume_l[tid]);
}

// ---------------- fused consumer: den/recon GEMMs + forward/tm reductions ----------------
__global__ __launch_bounds__(256) void k_consumer(const short* __restrict__ dis_v,
                                                  const short* __restrict__ thetan_b,
                                                  const short* __restrict__ thetas_b,
                                                  const short* __restrict__ bows_b,
                                                  float* __restrict__ fwd_acc,
                                                  float* __restrict__ tm_acc){
  __shared__ float fwd_l[B_];
  __shared__ float tm_l;
  int tid = threadIdx.x;
  for(int i = tid; i < B_; i += 256) fwd_l[i] = 0.f;
  if(tid == 0) tm_l = 0.f;
  __syncthreads();
  int w = tid >> 6, lane = tid & 63, lm = lane & 15, q = lane >> 4;
  int v0 = blockIdx.x * 64;
  int vrow = v0 + w * 16 + lm;
  s8v disf[7];
  #pragma unroll
  for(int i = 0; i < 7; i++)
    disf[i] = *(const s8v*)&dis_v[(long)vrow * KP + i * 32 + q * 8];

  float tmreg = 0.f;
  for(int cb = 0; cb < 32; cb++){
    int b0 = cb * 16;
    f32x4 aD = {0.f,0.f,0.f,0.f}, aR = {0.f,0.f,0.f,0.f};
    #pragma unroll
    for(int i = 0; i < 7; i++){
      long off = (long)(b0 + lm) * KP + i * 32 + q * 8;
      s8v tn = *(const s8v*)&thetan_b[off];
      s8v ts = *(const s8v*)&thetas_b[off];
      aD = mfma16(disf[i], tn, aD);
      aR = mfma16(disf[i], ts, aR);
    }
    int bg = b0 + lm;
    short4 bw4 = *(const short4*)&bows_b[(long)bg * VP + v0 + w * 16 + q * 4];
    float fwd_p = 0.f;
    #pragma unroll
    for(int r = 0; r < 4; r++){
      float bv = __uint_as_float(((unsigned)(unsigned short)(&bw4.x)[r]) << 16);
      float den = aD[r] + 1e-30f;
      float rec = aR[r];
      fwd_p += bv / den;          // num == 1 (cost*dis == 1 algebraically)
      float lg = bv < 1.5f ? 0.f : (bv < 2.5f ? 0.69314718056f :
                 (bv < 3.5f ? 1.79175946923f : 3.17805383035f));
      tmreg += bv * __logf(rec + 1e-10f) - rec - lg;
    }
    fwd_p += __shfl_xor(fwd_p, 16, 64); fwd_p += __shfl_xor(fwd_p, 32, 64);
    if(q == 0) atomicAdd(&fwd_l[bg], fwd_p);
  }
  #pragma unroll
  for(int s = 32; s >= 1; s >>= 1) tmreg += __shfl_xor(tmreg, s, 64);
  if(lane == 0) atomicAdd(&tm_l, tmreg);
  __syncthreads();
  for(int i = tid; i < B_; i += 256) atomicAdd(&fwd_acc[i], fwd_l[i]);
  if(tid == 0) atomicAdd(tm_acc, tm_l);
}

// ---------------- colsum = bows@dis (split-K, atomic) ----------------
__global__ __launch_bounds__(256) void k_colsum(const short* __restrict__ bows_b,
                                                const short* __restrict__ dis_t,
                                                float* __restrict__ colsum_acc){
  __shared__ short As[128 * 32];
  __shared__ short BsD[64 * 32];
  int tid = threadIdx.x, w = tid >> 6, lane = tid & 63, lm = lane & 15, q = lane >> 4;
  int m0 = blockIdx.x * 128, t0 = blockIdx.y * 64;
  long kstart = (long)blockIdx.z * 2112;
  long kend = kstart + 2112; if(kend > VP) kend = VP;
  int rsub = lane >> 2;
  int kl = (lane & 3) * 8;
  int rA0 = m0 + w * 16 + rsub;
  int rA1 = m0 + (w + 4) * 16 + rsub;
  int tB = t0 + w * 16 + rsub; if(tB > KP - 1) tB = KP - 1;   // rows >= KT are zeros
  f32x4 accD[2][4];
  #pragma unroll
  for(int i = 0; i < 2; i++)
    #pragma unroll
    for(int j = 0; j < 4; j++) accD[i][j] = (f32x4){0.f,0.f,0.f,0.f};

  for(long kb = kstart; kb < kend; kb += 32){
    load_lds16(&bows_b[(long)rA0 * VP + kb + kl], &As[w * 512]);
    load_lds16(&bows_b[(long)rA1 * VP + kb + kl], &As[(w + 4) * 512]);
    load_lds16(&dis_t[(long)tB * VP + kb + kl], &BsD[w * 512]);
    __syncthreads();
    s8v af[2], bd[4];
    #pragma unroll
    for(int i = 0; i < 2; i++) af[i] = *(const s8v*)&As[(w * 32 + i * 16 + lm) * 32 + q * 8];
    #pragma unroll
    for(int j = 0; j < 4; j++) bd[j] = *(const s8v*)&BsD[(j * 16 + lm) * 32 + q * 8];
    #pragma unroll
    for(int i = 0; i < 2; i++)
      #pragma unroll
      for(int j = 0; j < 4; j++)
        accD[i][j] = mfma16(af[i], bd[j], accD[i][j]);
    __syncthreads();
  }
  #pragma unroll
  for(int i = 0; i < 2; i++)
    #pragma unroll
    for(int j = 0; j < 4; j++){
      int doc = m0 + w * 32 + i * 16 + q * 4;
      int tg = t0 + j * 16 + lm;
      if(tg < KT){
        #pragma unroll
        for(int r = 0; r < 4; r++)
          atomicAdd(&colsum_acc[(long)(doc + r) * KT + tg], accD[i][j][r]);
      }
    }
}

// ---------------- per-doc backward + forward finalize ----------------
__global__ __launch_bounds__(64) void k_bwd(const float* __restrict__ colsum_acc,
                                            const float* __restrict__ thn_f,
                                            const float* __restrict__ fwd_acc,
                                            const float* __restrict__ ntok_acc,
                                            float* __restrict__ bwd_pd,
                                            float* __restrict__ fwd_pd){
  int b = blockIdx.x, lane = threadIdx.x;
  float s = 0.f;
  for(int t = lane; t < KT; t += 64)
    s += thn_f[(long)b * KT + t] / (colsum_acc[(long)b * KT + t] + 1e-30f);
  #pragma unroll
  for(int k = 32; k >= 1; k >>= 1) s += __shfl_xor(s, k, 64);
  if(lane == 0){
    float nt = ntok_acc[b];
    bwd_pd[b] = s * nt;                     // A[b,k] == ntok[b] (bows @ 1)
    fwd_pd[b] = fwd_acc[b] / fmaxf(nt, 1.f);
  }
}

// ---------------- final reduce + 3 outputs ----------------
__global__ __launch_bounds__(512) void k_final(const float* __restrict__ bwd_pd,
                                               const float* __restrict__ fwd_pd,
                                               const float* __restrict__ ntok_acc,
                                               const float* __restrict__ tm_acc,
                                               float* __restrict__ out){
  __shared__ float rf[8], rb[8];
  int tid = threadIdx.x, w = tid >> 6, lane = tid & 63;
  bool valid = ntok_acc[tid] > 0.f;
  float fw = valid ? fwd_pd[tid] : 0.f;
  float bw = valid ? bwd_pd[tid] : 0.f;
  #pragma unroll
  for(int s = 32; s >= 1; s >>= 1){ fw += __shfl_xor(fw, s, 64); bw += __shfl_xor(bw, s, 64); }
  if(lane == 0){ rf[w] = fw; rb[w] = bw; }
  __syncthreads();
  if(tid == 0){
    float F = 0.f, Bw = 0.f;
    #pragma unroll
    for(int i = 0; i < 8; i++){ F += rf[i]; Bw += rb[i]; }
    out[0] = 1.0f * (-tm_acc[0] / (float)B_);  // EPSILON * tm
    out[1] = 0.5f * F;                         // BETA * forward
    out[2] = 0.5f * Bw;                        // (1-BETA) * backward
  }
}

extern "C" void kernel_launch(void* const* d_in, const int* in_sizes, int n_in,
                              void* d_out, int out_size, void* d_ws, size_t ws_size,
                              hipStream_t stream){
  const float* bows  = (const float*)d_in[0];
  const float* rho   = (const float*)d_in[1];
  const float* alpha = (const float*)d_in[2];
  const float* W1    = (const float*)d_in[3];
  const float* b1    = (const float*)d_in[4];
  const float* W2    = (const float*)d_in[5];
  const float* b2    = (const float*)d_in[6];
  float* out = (float*)d_out;
  char* ws = (char*)d_ws;
  size_t o = 0;
  auto alloc = [&](size_t bytes) -> char* {
    char* p = ws + o; o = (o + bytes + 255) & ~(size_t)255; return p;
  };
  // zeroed region (contiguous, zeroed every launch)
  float* hid_acc    = (float*)alloc((size_t)B_ * HIDN * 4);
  float* colsum_acc = (float*)alloc((size_t)B_ * KT * 4);
  float* sumexp     = (float*)alloc(KP * 4);
  float* fwd_acc    = (float*)alloc(B_ * 4);
  float* ntok_acc   = (float*)alloc(B_ * 4);
  float* tm_acc     = (float*)alloc(256);
  float* bwd_pd     = (float*)alloc(B_ * 4);
  float* fwd_pd     = (float*)alloc(B_ * 4);
  size_t zbytes = o;
  // scratch (fully written before read)
  short* bows_b   = (short*)alloc((size_t)B_ * VP * 2);
  short* W1t      = (short*)alloc((size_t)HIDN * VP * 2);
  short* rho_p    = (short*)alloc((size_t)V_ * HP * 2);
  short* alpha_p  = (short*)alloc((size_t)KT * HP * 2);
  short* thetas_b = (short*)alloc((size_t)B_ * KP * 2);
  short* thetan_b = (short*)alloc((size_t)B_ * KP * 2);
  float* thetan_f = (float*)alloc((size_t)B_ * KT * 4);
  short* dis_t    = (short*)alloc((size_t)KP * VP * 2);
  short* dis_v    = (short*)alloc((size_t)VP * KP * 2);

  kzero<<<256, 256, 0, stream>>>((float*)ws, (long)(zbytes / 4));
  k_bows<<<dim3(25, 512), 256, 0, stream>>>(bows, bows_b, ntok_acc);
  k_transW1<<<dim3(VP / 32, HIDN / 32), 256, 0, stream>>>(W1, W1t);
  kconvpad<<<V_, HP, 0, stream>>>(rho, rho_p, HH, HP);
  kconvpad<<<KT, HP, 0, stream>>>(alpha, alpha_p, HH, HP);
  k_inner<<<dim3(VP / 128, 4), 256, 0, stream>>>(rho_p, alpha_p, dis_t, dis_v, sumexp);
  k_gemm1<<<dim3(4, 7, 32), 256, 0, stream>>>(bows_b, W1t, hid_acc);
  k_theta<<<B_, 256, 0, stream>>>(hid_acc, b1, W2, b2, sumexp, thetas_b, thetan_b, thetan_f);
  k_consumer<<<VP / 64, 256, 0, stream>>>(dis_v, thetan_b, thetas_b, bows_b, fwd_acc, tm_acc);
  k_colsum<<<dim3(4, 4, 24), 256, 0, stream>>>(bows_b, dis_t, colsum_acc);
  k_bwd<<<B_, 64, 0, stream>>>(colsum_acc, thetan_f, fwd_acc, ntok_acc, bwd_pd, fwd_pd);
  k_final<<<1, 512, 0, stream>>>(bwd_pd, fwd_pd, ntok_acc, tm_acc, out);
}

// Round 5
// 811.867 us; speedup vs baseline: 1.4031x; 1.0296x over previous
//
#include <hip/hip_runtime.h>

#define B_    512
#define V_    50000
#define VP    50048   // padded vocab (64*782)
#define KT    200     // topics
#define HH    300     // embedding dim
#define HIDN  800     // hidden
#define KP    224     // padded topic dim (7*32)
#define HP    320     // padded embedding dim (10*32)
#define NVB   782     // VP/64 v-blocks (consumer partials per doc)

typedef __attribute__((ext_vector_type(4))) float  f32x4;
typedef __attribute__((ext_vector_type(8))) short  s8v;
typedef __attribute__((ext_vector_type(8))) __bf16 bf16x8;
typedef unsigned int u32;

static __device__ __forceinline__ f32x4 mfma16(s8v a, s8v b, f32x4 c){
  return __builtin_amdgcn_mfma_f32_16x16x32_bf16(
      __builtin_bit_cast(bf16x8, a), __builtin_bit_cast(bf16x8, b), c, 0, 0, 0);
}
static __device__ __forceinline__ short f2bf(float f){
  unsigned u = __float_as_uint(f);
  u = (u + 0x7fffu + ((u >> 16) & 1u)) >> 16;
  return (short)u;
}
// async global->LDS, 16B per lane; LDS dest = wave-uniform base + lane*16
static __device__ __forceinline__ void load_lds16(const short* g, short* lds){
  __builtin_amdgcn_global_load_lds(
      (const __attribute__((address_space(1))) u32*)g,
      (__attribute__((address_space(3))) u32*)lds, 16, 0, 0);
}

// ---------------- zero init ----------------
__global__ void kzero(float* p, long n){
  long i = blockIdx.x * (long)blockDim.x + threadIdx.x;
  long st = (long)gridDim.x * blockDim.x;
  for(; i < n; i += st) p[i] = 0.f;
}

// ---------------- bows fp32 -> bf16 (rows padded to VP) + per-doc token counts ----------------
__global__ __launch_bounds__(256) void k_bows(const float* __restrict__ src,
                                              short* __restrict__ dst,
                                              float* __restrict__ ntok_acc){
  __shared__ float r4[4];
  int b = blockIdx.y;
  int c = blockIdx.x * 256 + threadIdx.x;          // chunk of 8 shorts
  int lane = threadIdx.x & 63, w = threadIdx.x >> 6;
  float s = 0.f;
  if(c < VP / 8){
    int v = c * 8;
    s8v o = {0,0,0,0,0,0,0,0};
    if(v + 8 <= V_){
      float4 a = *(const float4*)&src[(long)b * V_ + v];
      float4 d = *(const float4*)&src[(long)b * V_ + v + 4];
      o[0]=f2bf(a.x); o[1]=f2bf(a.y); o[2]=f2bf(a.z); o[3]=f2bf(a.w);
      o[4]=f2bf(d.x); o[5]=f2bf(d.y); o[6]=f2bf(d.z); o[7]=f2bf(d.w);
      s = a.x + a.y + a.z + a.w + d.x + d.y + d.z + d.w;
    }
    *(s8v*)&dst[(long)b * VP + v] = o;
  }
  #pragma unroll
  for(int k = 32; k >= 1; k >>= 1) s += __shfl_xor(s, k, 64);
  if(lane == 0) r4[w] = s;
  __syncthreads();
  if(threadIdx.x == 0) atomicAdd(&ntok_acc[b], r4[0] + r4[1] + r4[2] + r4[3]);
}

// ---------------- W1 (V x HIDN fp32) -> W1t (HIDN x VP bf16, transposed) ----------------
__global__ __launch_bounds__(256) void k_transW1(const float* __restrict__ W1,
                                                 short* __restrict__ W1t){
  __shared__ float tile[32][33];
  int v0 = blockIdx.x * 32, n0 = blockIdx.y * 32;
  int tid = threadIdx.x;
  int r = tid >> 3, c4 = (tid & 7) * 4;
  float4 val = {0.f,0.f,0.f,0.f};
  int v = v0 + r;
  if(v < V_) val = *(const float4*)&W1[(long)v * HIDN + n0 + c4];
  tile[r][c4+0] = val.x; tile[r][c4+1] = val.y; tile[r][c4+2] = val.z; tile[r][c4+3] = val.w;
  __syncthreads();
  short4 o;
  o.x = f2bf(tile[c4+0][r]); o.y = f2bf(tile[c4+1][r]);
  o.z = f2bf(tile[c4+2][r]); o.w = f2bf(tile[c4+3][r]);
  *(short4*)&W1t[(long)(n0 + r) * VP + v0 + c4] = o;
}

// ---------------- fp32 -> bf16 with row padding (blockDim = kpad) ----------------
__global__ void kconvpad(const float* __restrict__ src, short* __restrict__ dst,
                         int kin, int kpad){
  int r = blockIdx.x, c = threadIdx.x;
  float v = (c < kin) ? src[(long)r * kin + c] : 0.f;
  dst[(long)r * kpad + c] = f2bf(v);
}

// ---------------- GEMM1: hid_acc += bows @ W1 (split-K, atomic) ----------------
__global__ __launch_bounds__(256) void k_gemm1(const short* __restrict__ Ab,
                                               const short* __restrict__ Bb,
                                               float* __restrict__ Cacc){
  __shared__ short As[128 * 32];
  __shared__ short Bs[128 * 32];
  int tid = threadIdx.x, w = tid >> 6, lane = tid & 63, lm = lane & 15, q = lane >> 4;
  int m0 = blockIdx.x * 128, n0 = blockIdx.y * 128;
  long kstart = (long)blockIdx.z * 1568;
  long kend = kstart + 1568; if(kend > VP) kend = VP;
  int rsub = lane >> 2;          // 0..15 within 16-row chunk
  int kl = (lane & 3) * 8;       // shorts within 32-short row
  int rA0 = m0 + w * 16 + rsub;
  int rA1 = m0 + (w + 4) * 16 + rsub;
  int nB0 = n0 + w * 16 + rsub;       if(nB0 > HIDN - 1) nB0 = HIDN - 1;
  int nB1 = n0 + (w + 4) * 16 + rsub; if(nB1 > HIDN - 1) nB1 = HIDN - 1;
  f32x4 acc[2][8];
  #pragma unroll
  for(int i = 0; i < 2; i++)
    #pragma unroll
    for(int j = 0; j < 8; j++) acc[i][j] = (f32x4){0.f,0.f,0.f,0.f};

  for(long kb = kstart; kb < kend; kb += 32){
    load_lds16(&Ab[(long)rA0 * VP + kb + kl], &As[w * 512]);
    load_lds16(&Ab[(long)rA1 * VP + kb + kl], &As[(w + 4) * 512]);
    load_lds16(&Bb[(long)nB0 * VP + kb + kl], &Bs[w * 512]);
    load_lds16(&Bb[(long)nB1 * VP + kb + kl], &Bs[(w + 4) * 512]);
    __syncthreads();
    s8v af[2], bfr[8];
    #pragma unroll
    for(int i = 0; i < 2; i++) af[i]  = *(const s8v*)&As[(w * 32 + i * 16 + lm) * 32 + q * 8];
    #pragma unroll
    for(int j = 0; j < 8; j++) bfr[j] = *(const s8v*)&Bs[(j * 16 + lm) * 32 + q * 8];
    #pragma unroll
    for(int i = 0; i < 2; i++)
      #pragma unroll
      for(int j = 0; j < 8; j++)
        acc[i][j] = mfma16(af[i], bfr[j], acc[i][j]);
    __syncthreads();
  }
  #pragma unroll
  for(int i = 0; i < 2; i++)
    #pragma unroll
    for(int j = 0; j < 8; j++){
      int gm = m0 + w * 32 + i * 16 + q * 4;
      int gn = n0 + j * 16 + lm;
      if(gn < HIDN){
        #pragma unroll
        for(int r = 0; r < 4; r++) atomicAdd(&Cacc[(long)(gm + r) * HIDN + gn], acc[i][j][r]);
      }
    }
}

// ---------------- theta: relu(hid+b1) @ W2 + b2 -> softplus -> softmax / scaled ----------------
__global__ __launch_bounds__(256) void k_theta(const float* __restrict__ hid_acc,
                                               const float* __restrict__ b1,
                                               const float* __restrict__ W2,
                                               const float* __restrict__ b2,
                                               const float* __restrict__ sumexp,
                                               short* __restrict__ thetas_b,
                                               short* __restrict__ thetan_b,
                                               float* __restrict__ thetan_f){
  __shared__ float hrow[HIDN];
  __shared__ float thl[256];
  __shared__ float redm[4], reds[4];
  int b = blockIdx.x, tid = threadIdx.x;
  for(int h = tid; h < HIDN; h += 256){
    float x = hid_acc[(long)b * HIDN + h] + b1[h];
    hrow[h] = x > 0.f ? x : 0.f;
  }
  __syncthreads();
  float th = 0.f;
  if(tid < KT){
    float z = b2[tid];
    #pragma unroll 4
    for(int h = 0; h < HIDN; h++) z += hrow[h] * W2[h * KT + tid];
    th = (z > 0.f ? z : 0.f) + log1pf(expf(-fabsf(z)));   // softplus
  }
  thl[tid] = (tid < KT) ? th : -1e30f;
  __syncthreads();
  float m = thl[tid];
  #pragma unroll
  for(int s = 32; s >= 1; s >>= 1) m = fmaxf(m, __shfl_xor(m, s, 64));
  if((tid & 63) == 0) redm[tid >> 6] = m;
  __syncthreads();
  float mx = fmaxf(fmaxf(redm[0], redm[1]), fmaxf(redm[2], redm[3]));
  float e = (tid < KT) ? expf(th - mx) : 0.f;
  float s_ = e;
  #pragma unroll
  for(int s = 32; s >= 1; s >>= 1) s_ += __shfl_xor(s_, s, 64);
  if((tid & 63) == 0) reds[tid >> 6] = s_;
  __syncthreads();
  float sum = reds[0] + reds[1] + reds[2] + reds[3];
  if(tid < KP){
    short ts  = (tid < KT) ? f2bf(th / sumexp[tid]) : (short)0;  // theta / sum_v dis
    short tnb = (tid < KT) ? f2bf(e / sum) : (short)0;
    thetas_b[(long)b * KP + tid] = ts;
    thetan_b[(long)b * KP + tid] = tnb;
  }
  if(tid < KT) thetan_f[(long)b * KT + tid] = e / sum;
}

// ---------------- inner = rho @ alpha^T ; dis in topic-major (dis_t) + v-major (dis_v); sumexp ----------------
__global__ __launch_bounds__(256) void k_inner(const short* __restrict__ rho_p,
                                               const short* __restrict__ alpha_p,
                                               short* __restrict__ dis_t,
                                               short* __restrict__ dis_v,
                                               float* __restrict__ sumexp){
  __shared__ short As[128 * 40];
  __shared__ short Bs[64 * 40];
  __shared__ short tDis[128 * 72];
  __shared__ float sume_l[64];
  int tid = threadIdx.x, w = tid >> 6, lane = tid & 63, lm = lane & 15, q = lane >> 4;
  int v0 = blockIdx.x * 128, t0 = blockIdx.y * 64;
  if(tid < 64) sume_l[tid] = 0.f;
  __syncthreads();
  f32x4 acc[2][4];
  #pragma unroll
  for(int i = 0; i < 2; i++)
    #pragma unroll
    for(int j = 0; j < 4; j++) acc[i][j] = (f32x4){0.f,0.f,0.f,0.f};

  for(int h0 = 0; h0 < HP; h0 += 32){
    #pragma unroll
    for(int c0 = 0; c0 < 2; c0++){
      int c = tid + c0 * 256;
      int r = c >> 2, off = (c & 3) * 8;
      int vg = v0 + r;
      s8v v = {0,0,0,0,0,0,0,0};
      if(vg < V_) v = *(const s8v*)&rho_p[(long)vg * HP + h0 + off];
      *(s8v*)&As[r * 40 + off] = v;
    }
    {
      int r = tid >> 2, off = (tid & 3) * 8;
      int tg = t0 + r;
      s8v v = {0,0,0,0,0,0,0,0};
      if(tg < KT) v = *(const s8v*)&alpha_p[(long)tg * HP + h0 + off];
      *(s8v*)&Bs[r * 40 + off] = v;
    }
    __syncthreads();
    s8v af[2], bfr[4];
    #pragma unroll
    for(int i = 0; i < 2; i++) af[i]  = *(const s8v*)&As[(w * 32 + i * 16 + lm) * 40 + q * 8];
    #pragma unroll
    for(int j = 0; j < 4; j++) bfr[j] = *(const s8v*)&Bs[(j * 16 + lm) * 40 + q * 8];
    #pragma unroll
    for(int i = 0; i < 2; i++)
      #pragma unroll
      for(int j = 0; j < 4; j++)
        acc[i][j] = mfma16(af[i], bfr[j], acc[i][j]);
    __syncthreads();
  }
  // epilogue: dis into LDS tile (v-major, padded stride) + per-t exp sums
  #pragma unroll
  for(int i = 0; i < 2; i++)
    #pragma unroll
    for(int j = 0; j < 4; j++){
      int tg = t0 + j * 16 + lm;
      float s4 = 0.f;
      #pragma unroll
      for(int r = 0; r < 4; r++){
        int vloc = w * 32 + i * 16 + q * 4 + r;
        int vg = v0 + vloc;
        float x = acc[i][j][r];
        float e1 = __expf(x);  e1 = fminf(fmaxf(e1, 1e-30f), 1e10f);
        bool valid = (vg < V_) && (tg < KT);
        float dv = valid ? e1 : 0.f;
        tDis[vloc * 72 + (j * 16 + lm)] = f2bf(dv);
        s4 += dv;
      }
      s4 += __shfl_xor(s4, 16, 64);
      s4 += __shfl_xor(s4, 32, 64);
      if(q == 0) atomicAdd(&sume_l[j * 16 + lm], s4);
    }
  __syncthreads();
  // topic-major: dis_t[t][v], 16B contiguous in v  (guard: rows >= KP don't exist)
  for(int c = tid; c < 1024; c += 256){
    int t = c & 63, vch = c >> 6;          // vch 0..15
    int tg = t0 + t;
    if(tg < KP){
      s8v d;
      #pragma unroll
      for(int j = 0; j < 8; j++) d[j] = tDis[(vch * 8 + j) * 72 + t];
      *(s8v*)&dis_t[(long)tg * VP + v0 + vch * 8] = d;
    }
  }
  // v-major: dis_v[v][t], 16B contiguous in t  (guard: t0=192 block only owns cols 192..223)
  for(int c = tid; c < 1024; c += 256){
    int r = c >> 3, tch = (c & 7) * 8;     // r 0..127, tch 0..56
    if(t0 + tch < KP)
      *(s8v*)&dis_v[(long)(v0 + r) * KP + t0 + tch] = *(const s8v*)&tDis[r * 72 + tch];
  }
  if(tid < 64 && (t0 + tid) < KT) atomicAdd(&sumexp[t0 + tid], sume_l[tid]);
}

// ---------------- fused consumer: den/recon GEMMs + forward/tm reductions ----------------
// grid = (NVB, 4): blockIdx.y owns docs [y*128, y*128+128) -> ~3128 blocks for occupancy.
// Per-doc forward partials go to fwd_part[doc][bx] (no global atomics); tm 1 atomic/block.
__global__ __launch_bounds__(256) void k_consumer(const short* __restrict__ dis_v,
                                                  const short* __restrict__ thetan_b,
                                                  const short* __restrict__ thetas_b,
                                                  const short* __restrict__ bows_b,
                                                  float* __restrict__ fwd_part,
                                                  float* __restrict__ tm_acc){
  __shared__ float fwd_l[128];
  __shared__ float tm_l;
  int tid = threadIdx.x;
  if(tid < 128) fwd_l[tid] = 0.f;
  if(tid == 0) tm_l = 0.f;
  __syncthreads();
  int w = tid >> 6, lane = tid & 63, lm = lane & 15, q = lane >> 4;
  int bx = blockIdx.x, by = blockIdx.y;
  int v0 = bx * 64;
  int vrow = v0 + w * 16 + lm;
  s8v disf[7];
  #pragma unroll
  for(int i = 0; i < 7; i++)
    disf[i] = *(const s8v*)&dis_v[(long)vrow * KP + i * 32 + q * 8];

  float tmreg = 0.f;
  for(int cb = by * 8; cb < by * 8 + 8; cb++){
    int b0 = cb * 16;
    f32x4 aD = {0.f,0.f,0.f,0.f}, aR = {0.f,0.f,0.f,0.f};
    #pragma unroll
    for(int i = 0; i < 7; i++){
      long off = (long)(b0 + lm) * KP + i * 32 + q * 8;
      s8v tn = *(const s8v*)&thetan_b[off];
      s8v ts = *(const s8v*)&thetas_b[off];
      aD = mfma16(disf[i], tn, aD);
      aR = mfma16(disf[i], ts, aR);
    }
    int bg = b0 + lm;
    short4 bw4 = *(const short4*)&bows_b[(long)bg * VP + v0 + w * 16 + q * 4];
    float fwd_p = 0.f;
    #pragma unroll
    for(int r = 0; r < 4; r++){
      float bv = __uint_as_float(((unsigned)(unsigned short)(&bw4.x)[r]) << 16);
      float den = aD[r] + 1e-30f;
      float rec = aR[r];
      fwd_p += bv * __builtin_amdgcn_rcpf(den);   // num == 1 (cost*dis == 1)
      float lg = bv < 1.5f ? 0.f : (bv < 2.5f ? 0.69314718056f :
                 (bv < 3.5f ? 1.79175946923f : 3.17805383035f));
      tmreg += bv * __logf(rec + 1e-10f) - rec - lg;
    }
    fwd_p += __shfl_xor(fwd_p, 16, 64); fwd_p += __shfl_xor(fwd_p, 32, 64);
    if(q == 0) atomicAdd(&fwd_l[bg - by * 128], fwd_p);
  }
  #pragma unroll
  for(int s = 32; s >= 1; s >>= 1) tmreg += __shfl_xor(tmreg, s, 64);
  if(lane == 0) atomicAdd(&tm_l, tmreg);
  __syncthreads();
  if(tid < 128) fwd_part[(long)(by * 128 + tid) * NVB + bx] = fwd_l[tid];
  if(tid == 0) atomicAdd(tm_acc, tm_l);
}

// ---------------- colsum = bows@dis (split-K, atomic) ----------------
__global__ __launch_bounds__(256) void k_colsum(const short* __restrict__ bows_b,
                                                const short* __restrict__ dis_t,
                                                float* __restrict__ colsum_acc){
  __shared__ short As[128 * 32];
  __shared__ short BsD[64 * 32];
  int tid = threadIdx.x, w = tid >> 6, lane = tid & 63, lm = lane & 15, q = lane >> 4;
  int m0 = blockIdx.x * 128, t0 = blockIdx.y * 64;
  long kstart = (long)blockIdx.z * 2112;
  long kend = kstart + 2112; if(kend > VP) kend = VP;
  int rsub = lane >> 2;
  int kl = (lane & 3) * 8;
  int rA0 = m0 + w * 16 + rsub;
  int rA1 = m0 + (w + 4) * 16 + rsub;
  int tB = t0 + w * 16 + rsub; if(tB > KP - 1) tB = KP - 1;   // rows >= KT are zeros
  f32x4 accD[2][4];
  #pragma unroll
  for(int i = 0; i < 2; i++)
    #pragma unroll
    for(int j = 0; j < 4; j++) accD[i][j] = (f32x4){0.f,0.f,0.f,0.f};

  for(long kb = kstart; kb < kend; kb += 32){
    load_lds16(&bows_b[(long)rA0 * VP + kb + kl], &As[w * 512]);
    load_lds16(&bows_b[(long)rA1 * VP + kb + kl], &As[(w + 4) * 512]);
    load_lds16(&dis_t[(long)tB * VP + kb + kl], &BsD[w * 512]);
    __syncthreads();
    s8v af[2], bd[4];
    #pragma unroll
    for(int i = 0; i < 2; i++) af[i] = *(const s8v*)&As[(w * 32 + i * 16 + lm) * 32 + q * 8];
    #pragma unroll
    for(int j = 0; j < 4; j++) bd[j] = *(const s8v*)&BsD[(j * 16 + lm) * 32 + q * 8];
    #pragma unroll
    for(int i = 0; i < 2; i++)
      #pragma unroll
      for(int j = 0; j < 4; j++)
        accD[i][j] = mfma16(af[i], bd[j], accD[i][j]);
    __syncthreads();
  }
  #pragma unroll
  for(int i = 0; i < 2; i++)
    #pragma unroll
    for(int j = 0; j < 4; j++){
      int doc = m0 + w * 32 + i * 16 + q * 4;
      int tg = t0 + j * 16 + lm;
      if(tg < KT){
        #pragma unroll
        for(int r = 0; r < 4; r++)
          atomicAdd(&colsum_acc[(long)(doc + r) * KT + tg], accD[i][j][r]);
      }
    }
}

// ---------------- per-doc backward + forward finalize ----------------
__global__ __launch_bounds__(64) void k_bwd(const float* __restrict__ colsum_acc,
                                            const float* __restrict__ thn_f,
                                            const float* __restrict__ fwd_part,
                                            const float* __restrict__ ntok_acc,
                                            float* __restrict__ bwd_pd,
                                            float* __restrict__ fwd_pd){
  int b = blockIdx.x, lane = threadIdx.x;
  float s = 0.f;
  for(int t = lane; t < KT; t += 64)
    s += thn_f[(long)b * KT + t] * __builtin_amdgcn_rcpf(colsum_acc[(long)b * KT + t] + 1e-30f);
  float fp = 0.f;
  for(int p = lane; p < NVB; p += 64) fp += fwd_part[(long)b * NVB + p];
  #pragma unroll
  for(int k = 32; k >= 1; k >>= 1){ s += __shfl_xor(s, k, 64); fp += __shfl_xor(fp, k, 64); }
  if(lane == 0){
    float nt = ntok_acc[b];
    bwd_pd[b] = s * nt;                     // A[b,k] == ntok[b] (bows @ 1)
    fwd_pd[b] = fp / fmaxf(nt, 1.f);
  }
}

// ---------------- final reduce + 3 outputs ----------------
__global__ __launch_bounds__(512) void k_final(const float* __restrict__ bwd_pd,
                                               const float* __restrict__ fwd_pd,
                                               const float* __restrict__ ntok_acc,
                                               const float* __restrict__ tm_acc,
                                               float* __restrict__ out){
  __shared__ float rf[8], rb[8];
  int tid = threadIdx.x, w = tid >> 6, lane = tid & 63;
  bool valid = ntok_acc[tid] > 0.f;
  float fw = valid ? fwd_pd[tid] : 0.f;
  float bw = valid ? bwd_pd[tid] : 0.f;
  #pragma unroll
  for(int s = 32; s >= 1; s >>= 1){ fw += __shfl_xor(fw, s, 64); bw += __shfl_xor(bw, s, 64); }
  if(lane == 0){ rf[w] = fw; rb[w] = bw; }
  __syncthreads();
  if(tid == 0){
    float F = 0.f, Bw = 0.f;
    #pragma unroll
    for(int i = 0; i < 8; i++){ F += rf[i]; Bw += rb[i]; }
    out[0] = 1.0f * (-tm_acc[0] / (float)B_);  // EPSILON * tm
    out[1] = 0.5f * F;                         // BETA * forward
    out[2] = 0.5f * Bw;                        // (1-BETA) * backward
  }
}

extern "C" void kernel_launch(void* const* d_in, const int* in_sizes, int n_in,
                              void* d_out, int out_size, void* d_ws, size_t ws_size,
                              hipStream_t stream){
  const float* bows  = (const float*)d_in[0];
  const float* rho   = (const float*)d_in[1];
  const float* alpha = (const float*)d_in[2];
  const float* W1    = (const float*)d_in[3];
  const float* b1    = (const float*)d_in[4];
  const float* W2    = (const float*)d_in[5];
  const float* b2    = (const float*)d_in[6];
  float* out = (float*)d_out;
  char* ws = (char*)d_ws;
  size_t o = 0;
  auto alloc = [&](size_t bytes) -> char* {
    char* p = ws + o; o = (o + bytes + 255) & ~(size_t)255; return p;
  };
  // zeroed region (contiguous, zeroed every launch)
  float* hid_acc    = (float*)alloc((size_t)B_ * HIDN * 4);
  float* colsum_acc = (float*)alloc((size_t)B_ * KT * 4);
  float* sumexp     = (float*)alloc(KP * 4);
  float* ntok_acc   = (float*)alloc(B_ * 4);
  float* tm_acc     = (float*)alloc(256);
  float* bwd_pd     = (float*)alloc(B_ * 4);
  float* fwd_pd     = (float*)alloc(B_ * 4);
  size_t zbytes = o;
  // scratch (fully written before read)
  short* bows_b   = (short*)alloc((size_t)B_ * VP * 2);
  short* W1t      = (short*)alloc((size_t)HIDN * VP * 2);
  short* rho_p    = (short*)alloc((size_t)V_ * HP * 2);
  short* alpha_p  = (short*)alloc((size_t)KT * HP * 2);
  short* thetas_b = (short*)alloc((size_t)B_ * KP * 2);
  short* thetan_b = (short*)alloc((size_t)B_ * KP * 2);
  float* thetan_f = (float*)alloc((size_t)B_ * KT * 4);
  short* dis_t    = (short*)alloc((size_t)KP * VP * 2);
  short* dis_v    = (short*)alloc((size_t)VP * KP * 2);
  float* fwd_part = (float*)alloc((size_t)B_ * NVB * 4);

  kzero<<<256, 256, 0, stream>>>((float*)ws, (long)(zbytes / 4));
  k_bows<<<dim3(25, 512), 256, 0, stream>>>(bows, bows_b, ntok_acc);
  k_transW1<<<dim3(VP / 32, HIDN / 32), 256, 0, stream>>>(W1, W1t);
  kconvpad<<<V_, HP, 0, stream>>>(rho, rho_p, HH, HP);
  kconvpad<<<KT, HP, 0, stream>>>(alpha, alpha_p, HH, HP);
  k_inner<<<dim3(VP / 128, 4), 256, 0, stream>>>(rho_p, alpha_p, dis_t, dis_v, sumexp);
  k_gemm1<<<dim3(4, 7, 32), 256, 0, stream>>>(bows_b, W1t, hid_acc);
  k_theta<<<B_, 256, 0, stream>>>(hid_acc, b1, W2, b2, sumexp, thetas_b, thetan_b, thetan_f);
  k_consumer<<<dim3(NVB, 4), 256, 0, stream>>>(dis_v, thetan_b, thetas_b, bows_b,
                                               fwd_part, tm_acc);
  k_colsum<<<dim3(4, 4, 24), 256, 0, stream>>>(bows_b, dis_t, colsum_acc);
  k_bwd<<<B_, 64, 0, stream>>>(colsum_acc, thetan_f, fwd_part, ntok_acc, bwd_pd, fwd_pd);
  k_final<<<1, 512, 0, stream>>>(bwd_pd, fwd_pd, ntok_acc, tm_acc, out);
}